// Round 1
// baseline (752.066 us; speedup 1.0000x reference)
//
#include <hip/hip_runtime.h>
#include <hip/hip_bf16.h>

#define BATCH 16
#define DIM 64
#define RANK 32
#define H 128
#define W 128
#define HW (H*W)
#define NSLOT 32

static __device__ __forceinline__ float bu2f(unsigned short u) {
    return __uint_as_float(((unsigned)u) << 16);
}
static __device__ __forceinline__ unsigned short f2bu(float f) {
    union { __hip_bfloat16 h; unsigned short u; } cv;
    cv.h = __float2bfloat16(f);
    return cv.u;
}
static __device__ __forceinline__ float ulo(unsigned int w) { return __uint_as_float(w << 16); }
static __device__ __forceinline__ float uhi(unsigned int w) { return __uint_as_float(w & 0xffff0000u); }

// ---------------- routing ----------------
__global__ __launch_bounds__(256) void k_pool(const float* __restrict__ x,
                                              float* __restrict__ pooled) {
    int bc = blockIdx.x;  // b*64+c
    const float4* p = (const float4*)(x + (size_t)bc * HW);
    float s = 0.f;
    for (int i = threadIdx.x; i < HW / 4; i += 256) {
        float4 v = p[i];
        s += v.x + v.y + v.z + v.w;
    }
#pragma unroll
    for (int off = 32; off > 0; off >>= 1) s += __shfl_down(s, off);
    __shared__ float red[4];
    if ((threadIdx.x & 63) == 0) red[threadIdx.x >> 6] = s;
    __syncthreads();
    if (threadIdx.x == 0)
        pooled[bc] = (red[0] + red[1] + red[2] + red[3]) * (1.f / HW);
}

// writes slot table: slot s=2b+{0,1} -> (b, e, gate); plus gsum[b]
__global__ __launch_bounds__(64) void k_gate(const float* __restrict__ pooled,
                                             const float* __restrict__ freq_emb,
                                             const float* __restrict__ noise,
                                             const float* __restrict__ gate_w,
                                             const float* __restrict__ fgw,
                                             int* __restrict__ slot_e,
                                             float* __restrict__ slot_g,
                                             float* __restrict__ gsum) {
    int b = threadIdx.x;
    if (b >= BATCH) return;
    float lg[4];
    for (int e = 0; e < 4; e++) {
        float s = 0.f;
        for (int c = 0; c < 64; c++) s += pooled[b * 64 + c] * gate_w[e * 64 + c];
        for (int c = 0; c < 64; c++) s += freq_emb[b * 64 + c] * fgw[e * 64 + c];
        s += noise[b * 4 + e] * 0.25f;  // NOISE_STD = 1/E
        lg[e] = s;
    }
    float m = fmaxf(fmaxf(lg[0], lg[1]), fmaxf(lg[2], lg[3]));
    float sc[4], Z = 0.f;
    for (int e = 0; e < 4; e++) { sc[e] = expf(lg[e] - m); Z += sc[e]; }
    for (int e = 0; e < 4; e++) sc[e] /= Z;
    int i0 = 0;
    for (int e = 1; e < 4; e++) if (sc[e] > sc[i0]) i0 = e;
    int i1 = -1;
    for (int e = 0; e < 4; e++) {
        if (e == i0) continue;
        if (i1 < 0 || sc[e] > sc[i1]) i1 = e;
    }
    slot_e[2 * b] = i0;     slot_g[2 * b] = sc[i0];
    slot_e[2 * b + 1] = i1; slot_g[2 * b + 1] = sc[i1];
    gsum[b] = sc[i0] + sc[i1];
}

// ---------------- weight prep ----------------
// weff[e][c][j] = (j<32 ? q_w[e][j][:] : kv_w[e][j-32][:]) . p0[e][:][c]
__global__ __launch_bounds__(256) void k_weff(const float* __restrict__ q_w,
                                              const float* __restrict__ kv_w,
                                              const float* __restrict__ p0,
                                              float* __restrict__ weff) {
    int t = blockIdx.x * 256 + threadIdx.x;
    if (t >= 4 * 96 * 64) return;
    int c = t & 63;
    int j = (t >> 6) % 96;
    int e = t / (96 * 64);
    const float* p0p = p0 + (size_t)e * RANK * DIM;
    float s = 0.f;
    if (j < 32) {
        const float* qp = q_w + (e * 32 + j) * 32;
        for (int r = 0; r < 32; r++) s += qp[r] * p0p[r * DIM + c];
    } else {
        const float* kp = kv_w + (e * 64 + (j - 32)) * 32;
        for (int r = 0; r < 32; r++) s += kp[r] * p0p[r * DIM + c];
    }
    weff[(e * 64 + c) * 96 + j] = s;
}

// transpose po_w [e][oc][c]->[e][c][oc] and p1 [e][j][c]->[e][c][j]
__global__ __launch_bounds__(256) void k_xpose(const float* __restrict__ po_w,
                                               const float* __restrict__ p1,
                                               float* __restrict__ powf,
                                               float* __restrict__ p1f) {
    int t = blockIdx.x * 256 + threadIdx.x;  // 8192
    if (t < 4096) {
        int e = t >> 10, oc = (t >> 5) & 31, c = t & 31;
        powf[(e * 32 + c) * 32 + oc] = po_w[t];
    }
    int e = t >> 11, j = (t >> 6) & 31, c = t & 63;
    p1f[(e * 64 + c) * 32 + j] = p1[t];
}

// ---------------- slot pipeline ----------------
// conv1x1: qkvpre[slot][j][p] = sum_c weff[e][c][j] * x[b][c][p]
__global__ __launch_bounds__(256) void k_qkvpre(const float* __restrict__ x,
                                                const float* __restrict__ weff,
                                                const int* __restrict__ slot_e,
                                                unsigned short* __restrict__ qkvpre) {
    int t = blockIdx.x;               // slot*48 + tile*3 + jg
    int jg = t % 3;
    int tile = (t / 3) & 15;
    int slot = t / 48;
    int b = slot >> 1;
    int e = slot_e[slot];
    const float* wp = weff + e * 96 * 64 + jg * 32;
    int p0 = tile * 1024 + threadIdx.x * 4;
    const float* xb = x + (size_t)b * DIM * HW + p0;
    float a0[32], a1[32], a2[32], a3[32];
#pragma unroll
    for (int j = 0; j < 32; j++) { a0[j] = 0.f; a1[j] = 0.f; a2[j] = 0.f; a3[j] = 0.f; }
    for (int c = 0; c < DIM; c++) {
        float4 xv = *(const float4*)(xb + (size_t)c * HW);
        const float* wr = wp + c * 96;
#pragma unroll
        for (int j = 0; j < 32; j++) {
            float wv = wr[j];
            a0[j] += wv * xv.x; a1[j] += wv * xv.y; a2[j] += wv * xv.z; a3[j] += wv * xv.w;
        }
    }
    unsigned short* op = qkvpre + ((size_t)slot * 96 + jg * 32) * HW + p0;
#pragma unroll
    for (int j = 0; j < 32; j++) {
        ushort4 o4;
        o4.x = f2bu(a0[j]); o4.y = f2bu(a1[j]); o4.z = f2bu(a2[j]); o4.w = f2bu(a3[j]);
        *(ushort4*)(op + (size_t)j * HW) = o4;
    }
}

// fused depthwise: ch 0..31 -> 3x3 pad1 (q_dw), ch 32..95 -> 7x7 pad3 (kv_dw)
__global__ __launch_bounds__(256) void k_dw(const unsigned short* __restrict__ qkvpre,
                                            const float* __restrict__ q_dw,
                                            const float* __restrict__ kv_dw,
                                            const int* __restrict__ slot_e,
                                            unsigned short* __restrict__ qkv) {
    int t = blockIdx.x;               // slot*(96*16) + c*16 + tile
    int tile = t & 15;
    int c = (t >> 4) % 96;
    int slot = t / (96 * 16);
    int e = slot_e[slot];
    int tx = (threadIdx.x & 31) * 4;
    int ty = threadIdx.x >> 5;
    int y = tile * 8 + ty;
    const unsigned short* in = qkvpre + ((size_t)slot * 96 + c) * HW;
    float s0 = 0.f, s1 = 0.f, s2 = 0.f, s3 = 0.f;
    if (c < 32) {
        const float* wp = q_dw + (e * 32 + c) * 9;
#pragma unroll
        for (int ky = 0; ky < 3; ky++) {
            int yy = y + ky - 1;
            if (yy < 0 || yy >= H) continue;
            const unsigned short* row = in + yy * W;
            float r[6];
#pragma unroll
            for (int d = 0; d < 6; d++) {
                int xx = tx + d - 1;
                r[d] = (xx >= 0 && xx < W) ? bu2f(row[xx]) : 0.f;
            }
#pragma unroll
            for (int kx = 0; kx < 3; kx++) {
                float wv = wp[ky * 3 + kx];
                s0 += wv * r[kx]; s1 += wv * r[kx + 1]; s2 += wv * r[kx + 2]; s3 += wv * r[kx + 3];
            }
        }
    } else {
        const float* wp = kv_dw + (e * 64 + (c - 32)) * 49;
#pragma unroll
        for (int ky = 0; ky < 7; ky++) {
            int yy = y + ky - 3;
            if (yy < 0 || yy >= H) continue;
            const unsigned short* row = in + yy * W;
            float r[10];
#pragma unroll
            for (int d = 0; d < 10; d++) {
                int xx = tx + d - 3;
                r[d] = (xx >= 0 && xx < W) ? bu2f(row[xx]) : 0.f;
            }
#pragma unroll
            for (int kx = 0; kx < 7; kx++) {
                float wv = wp[ky * 7 + kx];
                s0 += wv * r[kx]; s1 += wv * r[kx + 1]; s2 += wv * r[kx + 2]; s3 += wv * r[kx + 3];
            }
        }
    }
    ushort4 o4; o4.x = f2bu(s0); o4.y = f2bu(s1); o4.z = f2bu(s2); o4.w = f2bu(s3);
    *(ushort4*)(qkv + ((size_t)slot * 96 + c) * HW + y * W + tx) = o4;
}

// per-8x8-patch circular conv, FMA-bound form:
// o[i][j] = sum_mi sum_dj q[mi][(j-dj)&7] * k[(i-mi)&7][dj]
// lane = (unit, row i), computes full 8-px output row; k quad reads are aligned b128.
__global__ __launch_bounds__(256) void k_circ(const unsigned short* __restrict__ qkv,
                                              unsigned short* __restrict__ obuf) {
    __shared__ float Qs[32][68];
    __shared__ float Kp[32][68];
    int u = threadIdx.x >> 3;      // 0..31 block-local unit
    int i = threadIdx.x & 7;       // row
    int U = blockIdx.x * 32 + u;   // unit = (slot, c, patch)
    int patch = U & 255;
    int c = (U >> 8) & 31;
    int slot = U >> 13;
    int py = patch >> 4, px = patch & 15;
    size_t rowbase = ((size_t)slot * 96 + c) * HW + (py * 8 + i) * W + px * 8;
    uint4 qu = *(const uint4*)(qkv + rowbase);
    uint4 ku = *(const uint4*)(qkv + rowbase + (size_t)32 * HW);
    float qr[8], kr[8];
    qr[0] = ulo(qu.x); qr[1] = uhi(qu.x); qr[2] = ulo(qu.y); qr[3] = uhi(qu.y);
    qr[4] = ulo(qu.z); qr[5] = uhi(qu.z); qr[6] = ulo(qu.w); qr[7] = uhi(qu.w);
    kr[0] = ulo(ku.x); kr[1] = uhi(ku.x); kr[2] = ulo(ku.y); kr[3] = uhi(ku.y);
    kr[4] = ulo(ku.z); kr[5] = uhi(ku.z); kr[6] = ulo(ku.w); kr[7] = uhi(ku.w);
    *(float4*)&Qs[u][i * 8] = *(float4*)&qr[0];
    *(float4*)&Qs[u][i * 8 + 4] = *(float4*)&qr[4];
    *(float4*)&Kp[u][i * 8] = *(float4*)&kr[0];
    *(float4*)&Kp[u][i * 8 + 4] = *(float4*)&kr[4];
    __syncthreads();
    float acc[8];
#pragma unroll
    for (int j = 0; j < 8; j++) acc[j] = 0.f;
#pragma unroll
    for (int mi = 0; mi < 8; mi++) {
        int r = (i - mi) & 7;
        float qv[8], ka[4], kb[4];
        *(float4*)&qv[0] = *(const float4*)&Qs[u][mi * 8];
        *(float4*)&qv[4] = *(const float4*)&Qs[u][mi * 8 + 4];
        *(float4*)&ka[0] = *(const float4*)&Kp[u][r * 8];
        *(float4*)&kb[0] = *(const float4*)&Kp[u][r * 8 + 4];
#pragma unroll
        for (int j = 0; j < 8; j++) {
            float s = acc[j];
#pragma unroll
            for (int t = 0; t < 4; t++) {
                s += ka[t] * qv[(j - t) & 7];
                s += kb[t] * qv[(j - 4 - t) & 7];
            }
            acc[j] = s;
        }
    }
    size_t obase = ((size_t)slot * 32 + c) * HW + (py * 8 + i) * W + px * 8;
    uint4 ov;
    ov.x = (unsigned)f2bu(acc[0]) | ((unsigned)f2bu(acc[1]) << 16);
    ov.y = (unsigned)f2bu(acc[2]) | ((unsigned)f2bu(acc[3]) << 16);
    ov.z = (unsigned)f2bu(acc[4]) | ((unsigned)f2bu(acc[5]) << 16);
    ov.w = (unsigned)f2bu(acc[6]) | ((unsigned)f2bu(acc[7]) << 16);
    *(uint4*)(obuf + obase) = ov;
}

// per-image fused tail: for both slots of image b:
// LN(obuf) -> *v -> po -> *silu(p1@shared) -> p2 -> combine with gsum*x -> out
__global__ __launch_bounds__(256) void k_tail(const unsigned short* __restrict__ obuf,
                                              const unsigned short* __restrict__ qkv,
                                              const float* __restrict__ shr,
                                              const float* __restrict__ x,
                                              const int* __restrict__ slot_e,
                                              const float* __restrict__ slot_g,
                                              const float* __restrict__ gsum,
                                              const float* __restrict__ powf,
                                              const float* __restrict__ po_b,
                                              const float* __restrict__ ln_w,
                                              const float* __restrict__ ln_b,
                                              const float* __restrict__ p1f,
                                              const float* __restrict__ p2,
                                              float* __restrict__ out) {
    int b = blockIdx.x >> 6;
    int p = ((blockIdx.x & 63) << 8) + threadIdx.x;
    float att[2][32];
    int eidx[2];
    float gv[2];
#pragma unroll
    for (int si = 0; si < 2; si++) {
        int slot = 2 * b + si;
        int e = slot_e[slot];
        eidx[si] = e;
        gv[si] = slot_g[slot];
        const unsigned short* op = obuf + (size_t)slot * 32 * HW + p;
        float o[32];
#pragma unroll
        for (int c = 0; c < 32; c++) o[c] = bu2f(op[(size_t)c * HW]);
        float mu = 0.f;
#pragma unroll
        for (int c = 0; c < 32; c++) mu += o[c];
        mu *= (1.f / 32.f);
        float var = 0.f;
#pragma unroll
        for (int c = 0; c < 32; c++) { float d = o[c] - mu; var += d * d; }
        float rinv = rsqrtf(var * (1.f / 32.f) + 1e-5f);
        const float* powp = powf + e * 1024;
        const float* lnwp = ln_w + e * 32;
        const float* lnbp = ln_b + e * 32;
        const float* pobp = po_b + e * 32;
        const unsigned short* vp = qkv + ((size_t)slot * 96 + 64) * HW + p;
#pragma unroll
        for (int j = 0; j < 32; j++) att[si][j] = pobp[j];
        for (int c = 0; c < 32; c++) {
            float uu = ((o[c] - mu) * rinv * lnwp[c] + lnbp[c]) * bu2f(vp[(size_t)c * HW]);
            const float* pr = powp + c * 32;
#pragma unroll
            for (int j = 0; j < 32; j++) att[si][j] += pr[j] * uu;
        }
        float t[32];
#pragma unroll
        for (int j = 0; j < 32; j++) t[j] = 0.f;
        const float* shp = shr + (size_t)b * 64 * HW + p;
        const float* p1p = p1f + e * 2048;
        for (int c = 0; c < 64; c++) {
            float sv = shp[(size_t)c * HW];
            const float* pr = p1p + c * 32;
#pragma unroll
            for (int j = 0; j < 32; j++) t[j] += pr[j] * sv;
        }
#pragma unroll
        for (int j = 0; j < 32; j++) {
            float tv = t[j];
            att[si][j] *= tv * __builtin_amdgcn_rcpf(1.f + __expf(-tv));
        }
    }
    float gs = gsum[b];
    const float* xp = x + (size_t)b * 64 * HW + p;
    float* oa = out + (size_t)b * 64 * HW + p;
    const float* p2a = p2 + eidx[0] * 2048;
    const float* p2b = p2 + eidx[1] * 2048;
    float g0 = gv[0], g1 = gv[1];
    for (int oc = 0; oc < 64; oc++) {
        const float* pa = p2a + oc * 32;
        const float* pb = p2b + oc * 32;
        float sa = 0.f, sb = 0.f;
#pragma unroll
        for (int j = 0; j < 32; j++) {
            sa += pa[j] * att[0][j];
            sb += pb[j] * att[1][j];
        }
        oa[(size_t)oc * HW] = g0 * sa + g1 * sb + gs * xp[(size_t)oc * HW];
    }
}

extern "C" void kernel_launch(void* const* d_in, const int* in_sizes, int n_in,
                              void* d_out, int out_size, void* d_ws, size_t ws_size,
                              hipStream_t stream) {
    (void)in_sizes; (void)n_in; (void)out_size; (void)ws_size;
    const float* x      = (const float*)d_in[0];
    const float* shr    = (const float*)d_in[1];
    const float* femb   = (const float*)d_in[2];
    const float* noise  = (const float*)d_in[3];
    const float* gate_w = (const float*)d_in[4];
    const float* fgw    = (const float*)d_in[5];
    const float* p0     = (const float*)d_in[6];
    const float* p1     = (const float*)d_in[7];
    const float* p2     = (const float*)d_in[8];
    const float* q_w    = (const float*)d_in[9];
    const float* q_dw   = (const float*)d_in[10];
    const float* kv_w   = (const float*)d_in[11];
    const float* kv_dw  = (const float*)d_in[12];
    const float* ln_w   = (const float*)d_in[13];
    const float* ln_b   = (const float*)d_in[14];
    const float* po_w   = (const float*)d_in[15];
    const float* po_b   = (const float*)d_in[16];
    float* out = (float*)d_out;

    float* fws = (float*)d_ws;
    float* pooled = fws; fws += 1024;
    float* gsum   = fws; fws += 16;
    float* slot_g = fws; fws += 32;
    int*   slot_e = (int*)fws; fws += 32;
    float* weff   = fws; fws += 4 * 96 * 64;
    float* powf   = fws; fws += 4096;
    float* p1f    = fws; fws += 8192;
    uintptr_t a = ((uintptr_t)fws + 255) & ~(uintptr_t)255;
    unsigned short* qkvpre = (unsigned short*)a;                      // 32*96*HW bf16 = 100.7 MB
    unsigned short* qkvb   = qkvpre + (size_t)NSLOT * 96 * HW;        // 100.7 MB
    unsigned short* obuf   = qkvb + (size_t)NSLOT * 96 * HW;          // 32*32*HW bf16 = 33.6 MB

    k_pool<<<1024, 256, 0, stream>>>(x, pooled);
    k_gate<<<1, 64, 0, stream>>>(pooled, femb, noise, gate_w, fgw, slot_e, slot_g, gsum);
    k_weff<<<96, 256, 0, stream>>>(q_w, kv_w, p0, weff);
    k_xpose<<<32, 256, 0, stream>>>(po_w, p1, powf, p1f);
    k_qkvpre<<<NSLOT * 48, 256, 0, stream>>>(x, weff, slot_e, qkvpre);
    k_dw<<<NSLOT * 96 * 16, 256, 0, stream>>>(qkvpre, q_dw, kv_dw, slot_e, qkvb);
    k_circ<<<NSLOT * 32 * 256 / 32, 256, 0, stream>>>(qkvb, obuf);
    k_tail<<<BATCH * 64, 256, 0, stream>>>(obuf, qkvb, shr, x, slot_e, slot_g, gsum,
                                           powf, po_b, ln_w, ln_b, p1f, p2, out);
}

// Round 2
// 569.931 us; speedup vs baseline: 1.3196x; 1.3196x over previous
//
#include <hip/hip_runtime.h>
#include <hip/hip_bf16.h>

#define BATCH 16
#define DIM 64
#define RANK 32
#define H 128
#define W 128
#define HW (H*W)
#define NSLOT 32

static __device__ __forceinline__ float bu2f(unsigned short u) {
    return __uint_as_float(((unsigned)u) << 16);
}
static __device__ __forceinline__ unsigned short f2bu(float f) {
    union { __hip_bfloat16 h; unsigned short u; } cv;
    cv.h = __float2bfloat16(f);
    return cv.u;
}
static __device__ __forceinline__ float ulo(unsigned int w) { return __uint_as_float(w << 16); }
static __device__ __forceinline__ float uhi(unsigned int w) { return __uint_as_float(w & 0xffff0000u); }

// ---------------- routing ----------------
__global__ __launch_bounds__(256) void k_pool(const float* __restrict__ x,
                                              float* __restrict__ pooled) {
    int bc = blockIdx.x;  // b*64+c
    const float4* p = (const float4*)(x + (size_t)bc * HW);
    float s = 0.f;
    for (int i = threadIdx.x; i < HW / 4; i += 256) {
        float4 v = p[i];
        s += v.x + v.y + v.z + v.w;
    }
#pragma unroll
    for (int off = 32; off > 0; off >>= 1) s += __shfl_down(s, off);
    __shared__ float red[4];
    if ((threadIdx.x & 63) == 0) red[threadIdx.x >> 6] = s;
    __syncthreads();
    if (threadIdx.x == 0)
        pooled[bc] = (red[0] + red[1] + red[2] + red[3]) * (1.f / HW);
}

// writes slot table: slot s=2b+{0,1} -> (b, e, gate); plus gsum[b]
__global__ __launch_bounds__(64) void k_gate(const float* __restrict__ pooled,
                                             const float* __restrict__ freq_emb,
                                             const float* __restrict__ noise,
                                             const float* __restrict__ gate_w,
                                             const float* __restrict__ fgw,
                                             int* __restrict__ slot_e,
                                             float* __restrict__ slot_g,
                                             float* __restrict__ gsum) {
    int b = threadIdx.x;
    if (b >= BATCH) return;
    float lg[4];
    for (int e = 0; e < 4; e++) {
        float s = 0.f;
        for (int c = 0; c < 64; c++) s += pooled[b * 64 + c] * gate_w[e * 64 + c];
        for (int c = 0; c < 64; c++) s += freq_emb[b * 64 + c] * fgw[e * 64 + c];
        s += noise[b * 4 + e] * 0.25f;  // NOISE_STD = 1/E
        lg[e] = s;
    }
    float m = fmaxf(fmaxf(lg[0], lg[1]), fmaxf(lg[2], lg[3]));
    float sc[4], Z = 0.f;
    for (int e = 0; e < 4; e++) { sc[e] = expf(lg[e] - m); Z += sc[e]; }
    for (int e = 0; e < 4; e++) sc[e] /= Z;
    int i0 = 0;
    for (int e = 1; e < 4; e++) if (sc[e] > sc[i0]) i0 = e;
    int i1 = -1;
    for (int e = 0; e < 4; e++) {
        if (e == i0) continue;
        if (i1 < 0 || sc[e] > sc[i1]) i1 = e;
    }
    slot_e[2 * b] = i0;     slot_g[2 * b] = sc[i0];
    slot_e[2 * b + 1] = i1; slot_g[2 * b + 1] = sc[i1];
    gsum[b] = sc[i0] + sc[i1];
}

// ---------------- weight prep ----------------
// weff[e][c][j] = (j<32 ? q_w[e][j][:] : kv_w[e][j-32][:]) . p0[e][:][c]
__global__ __launch_bounds__(256) void k_weff(const float* __restrict__ q_w,
                                              const float* __restrict__ kv_w,
                                              const float* __restrict__ p0,
                                              float* __restrict__ weff) {
    int t = blockIdx.x * 256 + threadIdx.x;
    if (t >= 4 * 96 * 64) return;
    int c = t & 63;
    int j = (t >> 6) % 96;
    int e = t / (96 * 64);
    const float* p0p = p0 + (size_t)e * RANK * DIM;
    float s = 0.f;
    if (j < 32) {
        const float* qp = q_w + (e * 32 + j) * 32;
        for (int r = 0; r < 32; r++) s += qp[r] * p0p[r * DIM + c];
    } else {
        const float* kp = kv_w + (e * 64 + (j - 32)) * 32;
        for (int r = 0; r < 32; r++) s += kp[r] * p0p[r * DIM + c];
    }
    weff[(e * 64 + c) * 96 + j] = s;
}

// transpose po_w [e][oc][c]->[e][c][oc] and p1 [e][j][c]->[e][c][j]
__global__ __launch_bounds__(256) void k_xpose(const float* __restrict__ po_w,
                                               const float* __restrict__ p1,
                                               float* __restrict__ powf,
                                               float* __restrict__ p1f) {
    int t = blockIdx.x * 256 + threadIdx.x;  // 8192
    if (t < 4096) {
        int e = t >> 10, oc = (t >> 5) & 31, c = t & 31;
        powf[(e * 32 + c) * 32 + oc] = po_w[t];
    }
    int e = t >> 11, j = (t >> 6) & 31, c = t & 63;
    p1f[(e * 64 + c) * 32 + j] = p1[t];
}

// ---------------- slot pipeline ----------------
// conv1x1: qkvpre[slot][j][p] = sum_c weff[e][c][j] * x[b][c][p]
__global__ __launch_bounds__(256) void k_qkvpre(const float* __restrict__ x,
                                                const float* __restrict__ weff,
                                                const int* __restrict__ slot_e,
                                                unsigned short* __restrict__ qkvpre) {
    int t = blockIdx.x;               // slot*48 + tile*3 + jg
    int jg = t % 3;
    int tile = (t / 3) & 15;
    int slot = t / 48;
    int b = slot >> 1;
    int e = slot_e[slot];
    const float* wp = weff + e * 96 * 64 + jg * 32;
    int p0 = tile * 1024 + threadIdx.x * 4;
    const float* xb = x + (size_t)b * DIM * HW + p0;
    float a0[32], a1[32], a2[32], a3[32];
#pragma unroll
    for (int j = 0; j < 32; j++) { a0[j] = 0.f; a1[j] = 0.f; a2[j] = 0.f; a3[j] = 0.f; }
    for (int c = 0; c < DIM; c++) {
        float4 xv = *(const float4*)(xb + (size_t)c * HW);
        const float* wr = wp + c * 96;
#pragma unroll
        for (int j = 0; j < 32; j++) {
            float wv = wr[j];
            a0[j] += wv * xv.x; a1[j] += wv * xv.y; a2[j] += wv * xv.z; a3[j] += wv * xv.w;
        }
    }
    unsigned short* op = qkvpre + ((size_t)slot * 96 + jg * 32) * HW + p0;
#pragma unroll
    for (int j = 0; j < 32; j++) {
        ushort4 o4;
        o4.x = f2bu(a0[j]); o4.y = f2bu(a1[j]); o4.z = f2bu(a2[j]); o4.w = f2bu(a3[j]);
        *(ushort4*)(op + (size_t)j * HW) = o4;
    }
}

// fused depthwise, LDS-tiled: ch 0..31 -> 3x3 pad1 (q_dw), ch 32..95 -> 7x7 pad3 (kv_dw)
// block = (slot, c, 32-row tile); stage 38x128 bf16 rows in LDS with 8-ushort zero
// pads each side (W-boundary handled by pad, no inner-loop bounds checks);
// thread computes 4x4 output pixels, 10 (or 6) LDS row-loads with full reuse.
__global__ __launch_bounds__(256) void k_dw(const unsigned short* __restrict__ qkvpre,
                                            const float* __restrict__ q_dw,
                                            const float* __restrict__ kv_dw,
                                            const int* __restrict__ slot_e,
                                            unsigned short* __restrict__ qkv) {
    __shared__ unsigned short S[38][144];   // [8 pad][128 data][8 pad], row 288B (16B-aligned)
    int t = blockIdx.x;                     // slot*(96*4) + c*4 + tile
    int tile = t & 3;
    int c = (t >> 2) % 96;
    int slot = t / (96 * 4);
    int e = slot_e[slot];
    const unsigned short* in = qkvpre + ((size_t)slot * 96 + c) * HW;
    int y0 = tile * 32 - 3;

    // hoist weights to registers (uniform broadcast loads, L1-resident)
    float wk[49];
    if (c < 32) {
        const float* wp = q_dw + (e * 32 + c) * 9;
#pragma unroll
        for (int i = 0; i < 9; i++) wk[i] = wp[i];
    } else {
        const float* wp = kv_dw + (e * 64 + (c - 32)) * 49;
#pragma unroll
        for (int i = 0; i < 49; i++) wk[i] = wp[i];
    }

    // stage 38 rows x 128 px, vectorized 8-ushort loads; zero-fill OOB rows
    for (int i = threadIdx.x; i < 38 * 16; i += 256) {
        int r = i >> 4;
        int xc = (i & 15) << 3;
        int yy = y0 + r;
        uint4 v = make_uint4(0u, 0u, 0u, 0u);
        if (yy >= 0 && yy < H) v = *(const uint4*)(in + (size_t)yy * W + xc);
        *(uint4*)&S[r][8 + xc] = v;
    }
    // zero the side pads
    for (int i = threadIdx.x; i < 38 * 2; i += 256) {
        int r = i >> 1;
        *(uint4*)&S[r][(i & 1) ? 136 : 0] = make_uint4(0u, 0u, 0u, 0u);
    }
    __syncthreads();

    int tx = (threadIdx.x & 31) * 4;        // output col base
    int ty0 = (threadIdx.x >> 5) * 4;       // output row base within tile
    float acc[4][4];
#pragma unroll
    for (int a_ = 0; a_ < 4; a_++)
#pragma unroll
        for (int b_ = 0; b_ < 4; b_++) acc[a_][b_] = 0.f;

    if (c < 32) {
        // 3x3: output row ly taps staged rows ty0+2+ly+ky-? -> srow = ty0+2+rr, rr=ly+ky
#pragma unroll
        for (int rr = 0; rr < 6; rr++) {
            int srow = ty0 + 2 + rr;
            float px[12];
            uint2 w0 = *(const uint2*)&S[srow][4 + tx];
            uint2 w1 = *(const uint2*)&S[srow][8 + tx];
            uint2 w2 = *(const uint2*)&S[srow][12 + tx];
            px[0] = ulo(w0.x); px[1] = uhi(w0.x); px[2] = ulo(w0.y); px[3] = uhi(w0.y);
            px[4] = ulo(w1.x); px[5] = uhi(w1.x); px[6] = ulo(w1.y); px[7] = uhi(w1.y);
            px[8] = ulo(w2.x); px[9] = uhi(w2.x); px[10] = ulo(w2.y); px[11] = uhi(w2.y);
#pragma unroll
            for (int ly = 0; ly < 4; ly++) {
                int ky = rr - ly;
                if (ky < 0 || ky > 2) continue;
#pragma unroll
                for (int kx = 0; kx < 3; kx++) {
                    float wv = wk[ky * 3 + kx];
#pragma unroll
                    for (int j = 0; j < 4; j++) acc[ly][j] += wv * px[j + kx + 3];
                }
            }
        }
    } else {
        // 7x7: srow = ty0 + rr, rr = ly + ky in [0,9]
#pragma unroll
        for (int rr = 0; rr < 10; rr++) {
            int srow = ty0 + rr;
            float px[12];
            uint2 w0 = *(const uint2*)&S[srow][4 + tx];
            uint2 w1 = *(const uint2*)&S[srow][8 + tx];
            uint2 w2 = *(const uint2*)&S[srow][12 + tx];
            px[0] = ulo(w0.x); px[1] = uhi(w0.x); px[2] = ulo(w0.y); px[3] = uhi(w0.y);
            px[4] = ulo(w1.x); px[5] = uhi(w1.x); px[6] = ulo(w1.y); px[7] = uhi(w1.y);
            px[8] = ulo(w2.x); px[9] = uhi(w2.x); px[10] = ulo(w2.y); px[11] = uhi(w2.y);
#pragma unroll
            for (int ly = 0; ly < 4; ly++) {
                int ky = rr - ly;
                if (ky < 0 || ky > 6) continue;
#pragma unroll
                for (int kx = 0; kx < 7; kx++) {
                    float wv = wk[ky * 7 + kx];
#pragma unroll
                    for (int j = 0; j < 4; j++) acc[ly][j] += wv * px[j + kx + 1];
                }
            }
        }
    }

    unsigned short* op = qkv + ((size_t)slot * 96 + c) * HW;
    int ybase = tile * 32 + ty0;
#pragma unroll
    for (int ly = 0; ly < 4; ly++) {
        ushort4 o4;
        o4.x = f2bu(acc[ly][0]); o4.y = f2bu(acc[ly][1]);
        o4.z = f2bu(acc[ly][2]); o4.w = f2bu(acc[ly][3]);
        *(ushort4*)(op + (size_t)(ybase + ly) * W + tx) = o4;
    }
}

// per-8x8-patch circular conv, FMA-bound form:
// o[i][j] = sum_mi sum_dj q[mi][(j-dj)&7] * k[(i-mi)&7][dj]
// lane = (unit, row i), computes full 8-px output row; k quad reads are aligned b128.
__global__ __launch_bounds__(256) void k_circ(const unsigned short* __restrict__ qkv,
                                              unsigned short* __restrict__ obuf) {
    __shared__ float Qs[32][68];
    __shared__ float Kp[32][68];
    int u = threadIdx.x >> 3;      // 0..31 block-local unit
    int i = threadIdx.x & 7;       // row
    int U = blockIdx.x * 32 + u;   // unit = (slot, c, patch)
    int patch = U & 255;
    int c = (U >> 8) & 31;
    int slot = U >> 13;
    int py = patch >> 4, px = patch & 15;
    size_t rowbase = ((size_t)slot * 96 + c) * HW + (py * 8 + i) * W + px * 8;
    uint4 qu = *(const uint4*)(qkv + rowbase);
    uint4 ku = *(const uint4*)(qkv + rowbase + (size_t)32 * HW);
    float qr[8], kr[8];
    qr[0] = ulo(qu.x); qr[1] = uhi(qu.x); qr[2] = ulo(qu.y); qr[3] = uhi(qu.y);
    qr[4] = ulo(qu.z); qr[5] = uhi(qu.z); qr[6] = ulo(qu.w); qr[7] = uhi(qu.w);
    kr[0] = ulo(ku.x); kr[1] = uhi(ku.x); kr[2] = ulo(ku.y); kr[3] = uhi(ku.y);
    kr[4] = ulo(ku.z); kr[5] = uhi(ku.z); kr[6] = ulo(ku.w); kr[7] = uhi(ku.w);
    *(float4*)&Qs[u][i * 8] = *(float4*)&qr[0];
    *(float4*)&Qs[u][i * 8 + 4] = *(float4*)&qr[4];
    *(float4*)&Kp[u][i * 8] = *(float4*)&kr[0];
    *(float4*)&Kp[u][i * 8 + 4] = *(float4*)&kr[4];
    __syncthreads();
    float acc[8];
#pragma unroll
    for (int j = 0; j < 8; j++) acc[j] = 0.f;
#pragma unroll
    for (int mi = 0; mi < 8; mi++) {
        int r = (i - mi) & 7;
        float qv[8], ka[4], kb[4];
        *(float4*)&qv[0] = *(const float4*)&Qs[u][mi * 8];
        *(float4*)&qv[4] = *(const float4*)&Qs[u][mi * 8 + 4];
        *(float4*)&ka[0] = *(const float4*)&Kp[u][r * 8];
        *(float4*)&kb[0] = *(const float4*)&Kp[u][r * 8 + 4];
#pragma unroll
        for (int j = 0; j < 8; j++) {
            float s = acc[j];
#pragma unroll
            for (int t = 0; t < 4; t++) {
                s += ka[t] * qv[(j - t) & 7];
                s += kb[t] * qv[(j - 4 - t) & 7];
            }
            acc[j] = s;
        }
    }
    size_t obase = ((size_t)slot * 32 + c) * HW + (py * 8 + i) * W + px * 8;
    uint4 ov;
    ov.x = (unsigned)f2bu(acc[0]) | ((unsigned)f2bu(acc[1]) << 16);
    ov.y = (unsigned)f2bu(acc[2]) | ((unsigned)f2bu(acc[3]) << 16);
    ov.z = (unsigned)f2bu(acc[4]) | ((unsigned)f2bu(acc[5]) << 16);
    ov.w = (unsigned)f2bu(acc[6]) | ((unsigned)f2bu(acc[7]) << 16);
    *(uint4*)(obuf + obase) = ov;
}

// per-image fused tail: for both slots of image b:
// LN(obuf) -> *v -> po -> *silu(p1@shared) -> p2 -> combine with gsum*x -> out
__global__ __launch_bounds__(256) void k_tail(const unsigned short* __restrict__ obuf,
                                              const unsigned short* __restrict__ qkv,
                                              const float* __restrict__ shr,
                                              const float* __restrict__ x,
                                              const int* __restrict__ slot_e,
                                              const float* __restrict__ slot_g,
                                              const float* __restrict__ gsum,
                                              const float* __restrict__ powf,
                                              const float* __restrict__ po_b,
                                              const float* __restrict__ ln_w,
                                              const float* __restrict__ ln_b,
                                              const float* __restrict__ p1f,
                                              const float* __restrict__ p2,
                                              float* __restrict__ out) {
    int b = blockIdx.x >> 6;
    int p = ((blockIdx.x & 63) << 8) + threadIdx.x;
    float att[2][32];
    int eidx[2];
    float gv[2];
#pragma unroll
    for (int si = 0; si < 2; si++) {
        int slot = 2 * b + si;
        int e = slot_e[slot];
        eidx[si] = e;
        gv[si] = slot_g[slot];
        const unsigned short* op = obuf + (size_t)slot * 32 * HW + p;
        float o[32];
#pragma unroll
        for (int c = 0; c < 32; c++) o[c] = bu2f(op[(size_t)c * HW]);
        float mu = 0.f;
#pragma unroll
        for (int c = 0; c < 32; c++) mu += o[c];
        mu *= (1.f / 32.f);
        float var = 0.f;
#pragma unroll
        for (int c = 0; c < 32; c++) { float d = o[c] - mu; var += d * d; }
        float rinv = rsqrtf(var * (1.f / 32.f) + 1e-5f);
        const float* powp = powf + e * 1024;
        const float* lnwp = ln_w + e * 32;
        const float* lnbp = ln_b + e * 32;
        const float* pobp = po_b + e * 32;
        const unsigned short* vp = qkv + ((size_t)slot * 96 + 64) * HW + p;
#pragma unroll
        for (int j = 0; j < 32; j++) att[si][j] = pobp[j];
        for (int c = 0; c < 32; c++) {
            float uu = ((o[c] - mu) * rinv * lnwp[c] + lnbp[c]) * bu2f(vp[(size_t)c * HW]);
            const float* pr = powp + c * 32;
#pragma unroll
            for (int j = 0; j < 32; j++) att[si][j] += pr[j] * uu;
        }
        float t[32];
#pragma unroll
        for (int j = 0; j < 32; j++) t[j] = 0.f;
        const float* shp = shr + (size_t)b * 64 * HW + p;
        const float* p1p = p1f + e * 2048;
        for (int c = 0; c < 64; c++) {
            float sv = shp[(size_t)c * HW];
            const float* pr = p1p + c * 32;
#pragma unroll
            for (int j = 0; j < 32; j++) t[j] += pr[j] * sv;
        }
#pragma unroll
        for (int j = 0; j < 32; j++) {
            float tv = t[j];
            att[si][j] *= tv * __builtin_amdgcn_rcpf(1.f + __expf(-tv));
        }
    }
    float gs = gsum[b];
    const float* xp = x + (size_t)b * 64 * HW + p;
    float* oa = out + (size_t)b * 64 * HW + p;
    const float* p2a = p2 + eidx[0] * 2048;
    const float* p2b = p2 + eidx[1] * 2048;
    float g0 = gv[0], g1 = gv[1];
    for (int oc = 0; oc < 64; oc++) {
        const float* pa = p2a + oc * 32;
        const float* pb = p2b + oc * 32;
        float sa = 0.f, sb = 0.f;
#pragma unroll
        for (int j = 0; j < 32; j++) {
            sa += pa[j] * att[0][j];
            sb += pb[j] * att[1][j];
        }
        oa[(size_t)oc * HW] = g0 * sa + g1 * sb + gs * xp[(size_t)oc * HW];
    }
}

extern "C" void kernel_launch(void* const* d_in, const int* in_sizes, int n_in,
                              void* d_out, int out_size, void* d_ws, size_t ws_size,
                              hipStream_t stream) {
    (void)in_sizes; (void)n_in; (void)out_size; (void)ws_size;
    const float* x      = (const float*)d_in[0];
    const float* shr    = (const float*)d_in[1];
    const float* femb   = (const float*)d_in[2];
    const float* noise  = (const float*)d_in[3];
    const float* gate_w = (const float*)d_in[4];
    const float* fgw    = (const float*)d_in[5];
    const float* p0     = (const float*)d_in[6];
    const float* p1     = (const float*)d_in[7];
    const float* p2     = (const float*)d_in[8];
    const float* q_w    = (const float*)d_in[9];
    const float* q_dw   = (const float*)d_in[10];
    const float* kv_w   = (const float*)d_in[11];
    const float* kv_dw  = (const float*)d_in[12];
    const float* ln_w   = (const float*)d_in[13];
    const float* ln_b   = (const float*)d_in[14];
    const float* po_w   = (const float*)d_in[15];
    const float* po_b   = (const float*)d_in[16];
    float* out = (float*)d_out;

    float* fws = (float*)d_ws;
    float* pooled = fws; fws += 1024;
    float* gsum   = fws; fws += 16;
    float* slot_g = fws; fws += 32;
    int*   slot_e = (int*)fws; fws += 32;
    float* weff   = fws; fws += 4 * 96 * 64;
    float* powf   = fws; fws += 4096;
    float* p1f    = fws; fws += 8192;
    uintptr_t a = ((uintptr_t)fws + 255) & ~(uintptr_t)255;
    unsigned short* qkvpre = (unsigned short*)a;                      // 32*96*HW bf16 = 100.7 MB
    unsigned short* qkvb   = qkvpre + (size_t)NSLOT * 96 * HW;        // 100.7 MB
    unsigned short* obuf   = qkvb + (size_t)NSLOT * 96 * HW;          // 32*32*HW bf16 = 33.6 MB

    k_pool<<<1024, 256, 0, stream>>>(x, pooled);
    k_gate<<<1, 64, 0, stream>>>(pooled, femb, noise, gate_w, fgw, slot_e, slot_g, gsum);
    k_weff<<<96, 256, 0, stream>>>(q_w, kv_w, p0, weff);
    k_xpose<<<32, 256, 0, stream>>>(po_w, p1, powf, p1f);
    k_qkvpre<<<NSLOT * 48, 256, 0, stream>>>(x, weff, slot_e, qkvpre);
    k_dw<<<NSLOT * 96 * 4, 256, 0, stream>>>(qkvpre, q_dw, kv_dw, slot_e, qkvb);
    k_circ<<<NSLOT * 32 * 256 / 32, 256, 0, stream>>>(qkvb, obuf);
    k_tail<<<BATCH * 64, 256, 0, stream>>>(obuf, qkvb, shr, x, slot_e, slot_g, gsum,
                                           powf, po_b, ln_w, ln_b, p1f, p2, out);
}

// Round 4
// 487.255 us; speedup vs baseline: 1.5435x; 1.1697x over previous
//
#include <hip/hip_runtime.h>
#include <hip/hip_bf16.h>

#define BATCH 16
#define DIM 64
#define RANK 32
#define H 128
#define W 128
#define HW (H*W)
#define NSLOT 32

static __device__ __forceinline__ float bu2f(unsigned short u) {
    return __uint_as_float(((unsigned)u) << 16);
}
static __device__ __forceinline__ unsigned short f2bu(float f) {
    union { __hip_bfloat16 h; unsigned short u; } cv;
    cv.h = __float2bfloat16(f);
    return cv.u;
}
static __device__ __forceinline__ float ulo(unsigned int w) { return __uint_as_float(w << 16); }
static __device__ __forceinline__ float uhi(unsigned int w) { return __uint_as_float(w & 0xffff0000u); }

// ---------------- routing ----------------
__global__ __launch_bounds__(256) void k_pool(const float* __restrict__ x,
                                              float* __restrict__ pooled) {
    int bc = blockIdx.x;  // b*64+c
    const float4* p = (const float4*)(x + (size_t)bc * HW);
    float s = 0.f;
    for (int i = threadIdx.x; i < HW / 4; i += 256) {
        float4 v = p[i];
        s += v.x + v.y + v.z + v.w;
    }
#pragma unroll
    for (int off = 32; off > 0; off >>= 1) s += __shfl_down(s, off);
    __shared__ float red[4];
    if ((threadIdx.x & 63) == 0) red[threadIdx.x >> 6] = s;
    __syncthreads();
    if (threadIdx.x == 0)
        pooled[bc] = (red[0] + red[1] + red[2] + red[3]) * (1.f / HW);
}

// writes slot table: slot s=2b+{0,1} -> (b, e, gate); plus gsum[b]
__global__ __launch_bounds__(64) void k_gate(const float* __restrict__ pooled,
                                             const float* __restrict__ freq_emb,
                                             const float* __restrict__ noise,
                                             const float* __restrict__ gate_w,
                                             const float* __restrict__ fgw,
                                             int* __restrict__ slot_e,
                                             float* __restrict__ slot_g,
                                             float* __restrict__ gsum) {
    int b = threadIdx.x;
    if (b >= BATCH) return;
    float lg[4];
    for (int e = 0; e < 4; e++) {
        float s = 0.f;
        for (int c = 0; c < 64; c++) s += pooled[b * 64 + c] * gate_w[e * 64 + c];
        for (int c = 0; c < 64; c++) s += freq_emb[b * 64 + c] * fgw[e * 64 + c];
        s += noise[b * 4 + e] * 0.25f;  // NOISE_STD = 1/E
        lg[e] = s;
    }
    float m = fmaxf(fmaxf(lg[0], lg[1]), fmaxf(lg[2], lg[3]));
    float sc[4], Z = 0.f;
    for (int e = 0; e < 4; e++) { sc[e] = expf(lg[e] - m); Z += sc[e]; }
    for (int e = 0; e < 4; e++) sc[e] /= Z;
    int i0 = 0;
    for (int e = 1; e < 4; e++) if (sc[e] > sc[i0]) i0 = e;
    int i1 = -1;
    for (int e = 0; e < 4; e++) {
        if (e == i0) continue;
        if (i1 < 0 || sc[e] > sc[i1]) i1 = e;
    }
    slot_e[2 * b] = i0;     slot_g[2 * b] = sc[i0];
    slot_e[2 * b + 1] = i1; slot_g[2 * b + 1] = sc[i1];
    gsum[b] = sc[i0] + sc[i1];
}

// ---------------- weight prep ----------------
// weff[e][c][j] = (j<32 ? q_w[e][j][:] : kv_w[e][j-32][:]) . p0[e][:][c]
__global__ __launch_bounds__(256) void k_weff(const float* __restrict__ q_w,
                                              const float* __restrict__ kv_w,
                                              const float* __restrict__ p0,
                                              float* __restrict__ weff) {
    int t = blockIdx.x * 256 + threadIdx.x;
    if (t >= 4 * 96 * 64) return;
    int c = t & 63;
    int j = (t >> 6) % 96;
    int e = t / (96 * 64);
    const float* p0p = p0 + (size_t)e * RANK * DIM;
    float s = 0.f;
    if (j < 32) {
        const float* qp = q_w + (e * 32 + j) * 32;
        for (int r = 0; r < 32; r++) s += qp[r] * p0p[r * DIM + c];
    } else {
        const float* kp = kv_w + (e * 64 + (j - 32)) * 32;
        for (int r = 0; r < 32; r++) s += kp[r] * p0p[r * DIM + c];
    }
    weff[(e * 64 + c) * 96 + j] = s;
}

// transpose po_w [e][oc][c]->[e][c][oc] and p1 [e][j][c]->[e][c][j]
__global__ __launch_bounds__(256) void k_xpose(const float* __restrict__ po_w,
                                               const float* __restrict__ p1,
                                               float* __restrict__ powf,
                                               float* __restrict__ p1f) {
    int t = blockIdx.x * 256 + threadIdx.x;  // 8192
    if (t < 4096) {
        int e = t >> 10, oc = (t >> 5) & 31, c = t & 31;
        powf[(e * 32 + c) * 32 + oc] = po_w[t];
    }
    int e = t >> 11, j = (t >> 6) & 31, c = t & 63;
    p1f[(e * 64 + c) * 32 + j] = p1[t];
}

// ---------------- slot pipeline ----------------
// conv1x1: qkvpre[slot][j][p] = sum_c weff[e][c][j] * x[b][c][p]
__global__ __launch_bounds__(256) void k_qkvpre(const float* __restrict__ x,
                                                const float* __restrict__ weff,
                                                const int* __restrict__ slot_e,
                                                unsigned short* __restrict__ qkvpre) {
    int t = blockIdx.x;               // slot*48 + tile*3 + jg
    int jg = t % 3;
    int tile = (t / 3) & 15;
    int slot = t / 48;
    int b = slot >> 1;
    int e = slot_e[slot];
    const float* wp = weff + e * 96 * 64 + jg * 32;
    int p0 = tile * 1024 + threadIdx.x * 4;
    const float* xb = x + (size_t)b * DIM * HW + p0;
    float a0[32], a1[32], a2[32], a3[32];
#pragma unroll
    for (int j = 0; j < 32; j++) { a0[j] = 0.f; a1[j] = 0.f; a2[j] = 0.f; a3[j] = 0.f; }
    for (int c = 0; c < DIM; c++) {
        float4 xv = *(const float4*)(xb + (size_t)c * HW);
        const float* wr = wp + c * 96;
#pragma unroll
        for (int j = 0; j < 32; j++) {
            float wv = wr[j];
            a0[j] += wv * xv.x; a1[j] += wv * xv.y; a2[j] += wv * xv.z; a3[j] += wv * xv.w;
        }
    }
    unsigned short* op = qkvpre + ((size_t)slot * 96 + jg * 32) * HW + p0;
#pragma unroll
    for (int j = 0; j < 32; j++) {
        ushort4 o4;
        o4.x = f2bu(a0[j]); o4.y = f2bu(a1[j]); o4.z = f2bu(a2[j]); o4.w = f2bu(a3[j]);
        *(ushort4*)(op + (size_t)j * HW) = o4;
    }
}

// fused depthwise, LDS-tiled: ch 0..31 -> 3x3 pad1 (q_dw), ch 32..95 -> 7x7 pad3 (kv_dw)
__global__ __launch_bounds__(256) void k_dw(const unsigned short* __restrict__ qkvpre,
                                            const float* __restrict__ q_dw,
                                            const float* __restrict__ kv_dw,
                                            const int* __restrict__ slot_e,
                                            unsigned short* __restrict__ qkv) {
    __shared__ unsigned short S[38][144];   // [8 pad][128 data][8 pad], row 288B (16B-aligned)
    int t = blockIdx.x;                     // slot*(96*4) + c*4 + tile
    int tile = t & 3;
    int c = (t >> 2) % 96;
    int slot = t / (96 * 4);
    int e = slot_e[slot];
    const unsigned short* in = qkvpre + ((size_t)slot * 96 + c) * HW;
    int y0 = tile * 32 - 3;

    // hoist weights to registers (uniform broadcast loads, L1-resident)
    float wk[49];
    if (c < 32) {
        const float* wp = q_dw + (e * 32 + c) * 9;
#pragma unroll
        for (int i = 0; i < 9; i++) wk[i] = wp[i];
    } else {
        const float* wp = kv_dw + (e * 64 + (c - 32)) * 49;
#pragma unroll
        for (int i = 0; i < 49; i++) wk[i] = wp[i];
    }

    // stage 38 rows x 128 px, vectorized 8-ushort loads; zero-fill OOB rows
    for (int i = threadIdx.x; i < 38 * 16; i += 256) {
        int r = i >> 4;
        int xc = (i & 15) << 3;
        int yy = y0 + r;
        uint4 v = make_uint4(0u, 0u, 0u, 0u);
        if (yy >= 0 && yy < H) v = *(const uint4*)(in + (size_t)yy * W + xc);
        *(uint4*)&S[r][8 + xc] = v;
    }
    // zero the side pads
    for (int i = threadIdx.x; i < 38 * 2; i += 256) {
        int r = i >> 1;
        *(uint4*)&S[r][(i & 1) ? 136 : 0] = make_uint4(0u, 0u, 0u, 0u);
    }
    __syncthreads();

    int tx = (threadIdx.x & 31) * 4;        // output col base
    int ty0 = (threadIdx.x >> 5) * 4;       // output row base within tile
    float acc[4][4];
#pragma unroll
    for (int a_ = 0; a_ < 4; a_++)
#pragma unroll
        for (int b_ = 0; b_ < 4; b_++) acc[a_][b_] = 0.f;

    if (c < 32) {
#pragma unroll
        for (int rr = 0; rr < 6; rr++) {
            int srow = ty0 + 2 + rr;
            float px[12];
            uint2 w0 = *(const uint2*)&S[srow][4 + tx];
            uint2 w1 = *(const uint2*)&S[srow][8 + tx];
            uint2 w2 = *(const uint2*)&S[srow][12 + tx];
            px[0] = ulo(w0.x); px[1] = uhi(w0.x); px[2] = ulo(w0.y); px[3] = uhi(w0.y);
            px[4] = ulo(w1.x); px[5] = uhi(w1.x); px[6] = ulo(w1.y); px[7] = uhi(w1.y);
            px[8] = ulo(w2.x); px[9] = uhi(w2.x); px[10] = ulo(w2.y); px[11] = uhi(w2.y);
#pragma unroll
            for (int ly = 0; ly < 4; ly++) {
                int ky = rr - ly;
                if (ky < 0 || ky > 2) continue;
#pragma unroll
                for (int kx = 0; kx < 3; kx++) {
                    float wv = wk[ky * 3 + kx];
#pragma unroll
                    for (int j = 0; j < 4; j++) acc[ly][j] += wv * px[j + kx + 3];
                }
            }
        }
    } else {
#pragma unroll
        for (int rr = 0; rr < 10; rr++) {
            int srow = ty0 + rr;
            float px[12];
            uint2 w0 = *(const uint2*)&S[srow][4 + tx];
            uint2 w1 = *(const uint2*)&S[srow][8 + tx];
            uint2 w2 = *(const uint2*)&S[srow][12 + tx];
            px[0] = ulo(w0.x); px[1] = uhi(w0.x); px[2] = ulo(w0.y); px[3] = uhi(w0.y);
            px[4] = ulo(w1.x); px[5] = uhi(w1.x); px[6] = ulo(w1.y); px[7] = uhi(w1.y);
            px[8] = ulo(w2.x); px[9] = uhi(w2.x); px[10] = ulo(w2.y); px[11] = uhi(w2.y);
#pragma unroll
            for (int ly = 0; ly < 4; ly++) {
                int ky = rr - ly;
                if (ky < 0 || ky > 6) continue;
#pragma unroll
                for (int kx = 0; kx < 7; kx++) {
                    float wv = wk[ky * 7 + kx];
#pragma unroll
                    for (int j = 0; j < 4; j++) acc[ly][j] += wv * px[j + kx + 1];
                }
            }
        }
    }

    unsigned short* op = qkv + ((size_t)slot * 96 + c) * HW;
    int ybase = tile * 32 + ty0;
#pragma unroll
    for (int ly = 0; ly < 4; ly++) {
        ushort4 o4;
        o4.x = f2bu(acc[ly][0]); o4.y = f2bu(acc[ly][1]);
        o4.z = f2bu(acc[ly][2]); o4.w = f2bu(acc[ly][3]);
        *(ushort4*)(op + (size_t)(ybase + ly) * W + tx) = o4;
    }
}

// per-8x8-patch circular conv, FMA-bound form:
// o[i][j] = sum_mi sum_dj q[mi][(j-dj)&7] * k[(i-mi)&7][dj]
__global__ __launch_bounds__(256) void k_circ(const unsigned short* __restrict__ qkv,
                                              unsigned short* __restrict__ obuf) {
    __shared__ float Qs[32][68];
    __shared__ float Kp[32][68];
    int u = threadIdx.x >> 3;      // 0..31 block-local unit
    int i = threadIdx.x & 7;       // row
    int U = blockIdx.x * 32 + u;   // unit = (slot, c, patch)
    int patch = U & 255;
    int c = (U >> 8) & 31;
    int slot = U >> 13;
    int py = patch >> 4, px = patch & 15;
    size_t rowbase = ((size_t)slot * 96 + c) * HW + (py * 8 + i) * W + px * 8;
    uint4 qu = *(const uint4*)(qkv + rowbase);
    uint4 ku = *(const uint4*)(qkv + rowbase + (size_t)32 * HW);
    float qr[8], kr[8];
    qr[0] = ulo(qu.x); qr[1] = uhi(qu.x); qr[2] = ulo(qu.y); qr[3] = uhi(qu.y);
    qr[4] = ulo(qu.z); qr[5] = uhi(qu.z); qr[6] = ulo(qu.w); qr[7] = uhi(qu.w);
    kr[0] = ulo(ku.x); kr[1] = uhi(ku.x); kr[2] = ulo(ku.y); kr[3] = uhi(ku.y);
    kr[4] = ulo(ku.z); kr[5] = uhi(ku.z); kr[6] = ulo(ku.w); kr[7] = uhi(ku.w);
    *(float4*)&Qs[u][i * 8] = *(float4*)&qr[0];
    *(float4*)&Qs[u][i * 8 + 4] = *(float4*)&qr[4];
    *(float4*)&Kp[u][i * 8] = *(float4*)&kr[0];
    *(float4*)&Kp[u][i * 8 + 4] = *(float4*)&kr[4];
    __syncthreads();
    float acc[8];
#pragma unroll
    for (int j = 0; j < 8; j++) acc[j] = 0.f;
#pragma unroll
    for (int mi = 0; mi < 8; mi++) {
        int r = (i - mi) & 7;
        float qv[8], ka[4], kb[4];
        *(float4*)&qv[0] = *(const float4*)&Qs[u][mi * 8];
        *(float4*)&qv[4] = *(const float4*)&Qs[u][mi * 8 + 4];
        *(float4*)&ka[0] = *(const float4*)&Kp[u][r * 8];
        *(float4*)&kb[0] = *(const float4*)&Kp[u][r * 8 + 4];
#pragma unroll
        for (int j = 0; j < 8; j++) {
            float s = acc[j];
#pragma unroll
            for (int t = 0; t < 4; t++) {
                s += ka[t] * qv[(j - t) & 7];
                s += kb[t] * qv[(j - 4 - t) & 7];
            }
            acc[j] = s;
        }
    }
    size_t obase = ((size_t)slot * 32 + c) * HW + (py * 8 + i) * W + px * 8;
    uint4 ov;
    ov.x = (unsigned)f2bu(acc[0]) | ((unsigned)f2bu(acc[1]) << 16);
    ov.y = (unsigned)f2bu(acc[2]) | ((unsigned)f2bu(acc[3]) << 16);
    ov.z = (unsigned)f2bu(acc[4]) | ((unsigned)f2bu(acc[5]) << 16);
    ov.w = (unsigned)f2bu(acc[6]) | ((unsigned)f2bu(acc[7]) << 16);
    *(uint4*)(obuf + obase) = ov;
}

// per-slot attention tail: LN(obuf) -> *v -> po -> *silu(p1@shared) -> *gate
// stores attg[slot][p][32] bf16 (pixel-major: vectorized store & reload)
__global__ __launch_bounds__(256) void k_att(const unsigned short* __restrict__ obuf,
                                             const unsigned short* __restrict__ qkv,
                                             const float* __restrict__ shr,
                                             const int* __restrict__ slot_e,
                                             const float* __restrict__ slot_g,
                                             const float* __restrict__ powf,
                                             const float* __restrict__ po_b,
                                             const float* __restrict__ ln_w,
                                             const float* __restrict__ ln_b,
                                             const float* __restrict__ p1f,
                                             unsigned short* __restrict__ attg) {
    int slot = blockIdx.x >> 6;
    int p = ((blockIdx.x & 63) << 8) + threadIdx.x;
    int b = slot >> 1;
    int e = slot_e[slot];
    float g = slot_g[slot];

    // phase 1: LN(obuf)*v -> po accumulate
    const unsigned short* op = obuf + (size_t)slot * 32 * HW + p;
    float o[32];
#pragma unroll
    for (int c = 0; c < 32; c++) o[c] = bu2f(op[(size_t)c * HW]);
    float mu = 0.f;
#pragma unroll
    for (int c = 0; c < 32; c++) mu += o[c];
    mu *= (1.f / 32.f);
    float var = 0.f;
#pragma unroll
    for (int c = 0; c < 32; c++) { float d = o[c] - mu; var += d * d; }
    float rinv = rsqrtf(var * (1.f / 32.f) + 1e-5f);
    const float* powp = powf + e * 1024;
    const float* lnwp = ln_w + e * 32;
    const float* lnbp = ln_b + e * 32;
    const float* pobp = po_b + e * 32;
    const unsigned short* vp = qkv + ((size_t)slot * 96 + 64) * HW + p;
    float att[32];
#pragma unroll
    for (int j = 0; j < 32; j++) att[j] = pobp[j];
    for (int c = 0; c < 32; c++) {
        float uu = ((o[c] - mu) * rinv * lnwp[c] + lnbp[c]) * bu2f(vp[(size_t)c * HW]);
        const float* pr = powp + c * 32;
#pragma unroll
        for (int j = 0; j < 32; j++) att[j] += pr[j] * uu;
    }

    // phase 2: silu gate t = p1[e] @ shared
    float t[32];
#pragma unroll
    for (int j = 0; j < 32; j++) t[j] = 0.f;
    const float* shp = shr + (size_t)b * 64 * HW + p;
    const float* p1p = p1f + e * 2048;
    for (int c = 0; c < 64; c++) {
        float sv = shp[(size_t)c * HW];
        const float* pr = p1p + c * 32;
#pragma unroll
        for (int j = 0; j < 32; j++) t[j] += pr[j] * sv;
    }

    // gate + fold routing weight g, pack to bf16, vectorized store
    unsigned short* ap = attg + ((size_t)slot * HW + p) * 32;
    unsigned int wbuf[16];
#pragma unroll
    for (int jj = 0; jj < 16; jj++) {
        float t0 = t[2 * jj], t1 = t[2 * jj + 1];
        float a0 = g * att[2 * jj] * t0 * __builtin_amdgcn_rcpf(1.f + __expf(-t0));
        float a1 = g * att[2 * jj + 1] * t1 * __builtin_amdgcn_rcpf(1.f + __expf(-t1));
        wbuf[jj] = (unsigned)f2bu(a0) | ((unsigned)f2bu(a1) << 16);
    }
#pragma unroll
    for (int q = 0; q < 4; q++)
        *(uint4*)(ap + q * 8) = *(uint4*)&wbuf[q * 4];
}

// combine: out = p2_e0 @ attg0 + p2_e1 @ attg1 + gsum*x
// block = (b, px-tile, oc-half)
__global__ __launch_bounds__(256) void k_comb(const unsigned short* __restrict__ attg,
                                              const float* __restrict__ x,
                                              const int* __restrict__ slot_e,
                                              const float* __restrict__ gsum,
                                              const float* __restrict__ p2,
                                              float* __restrict__ out) {
    int t = blockIdx.x;
    int oh = t & 1;
    int tile = (t >> 1) & 63;
    int b = t >> 7;
    int p = (tile << 8) + threadIdx.x;

    const unsigned short* a0p = attg + ((size_t)(2 * b) * HW + p) * 32;
    const unsigned short* a1p = attg + ((size_t)(2 * b + 1) * HW + p) * 32;
    float a0[32], a1[32];
#pragma unroll
    for (int q = 0; q < 4; q++) {
        uint4 u0 = *(const uint4*)(a0p + q * 8);
        uint4 u1 = *(const uint4*)(a1p + q * 8);
        a0[q * 8 + 0] = ulo(u0.x); a0[q * 8 + 1] = uhi(u0.x);
        a0[q * 8 + 2] = ulo(u0.y); a0[q * 8 + 3] = uhi(u0.y);
        a0[q * 8 + 4] = ulo(u0.z); a0[q * 8 + 5] = uhi(u0.z);
        a0[q * 8 + 6] = ulo(u0.w); a0[q * 8 + 7] = uhi(u0.w);
        a1[q * 8 + 0] = ulo(u1.x); a1[q * 8 + 1] = uhi(u1.x);
        a1[q * 8 + 2] = ulo(u1.y); a1[q * 8 + 3] = uhi(u1.y);
        a1[q * 8 + 4] = ulo(u1.z); a1[q * 8 + 5] = uhi(u1.z);
        a1[q * 8 + 6] = ulo(u1.w); a1[q * 8 + 7] = uhi(u1.w);
    }
    int e0 = slot_e[2 * b], e1 = slot_e[2 * b + 1];
    float gs = gsum[b];
    const float* p2a = p2 + e0 * 2048 + oh * 1024;
    const float* p2b = p2 + e1 * 2048 + oh * 1024;
    const float* xp = x + ((size_t)b * 64 + oh * 32) * HW + p;
    float* oa = out + ((size_t)b * 64 + oh * 32) * HW + p;
    for (int oc = 0; oc < 32; oc++) {
        const float* pa = p2a + oc * 32;
        const float* pb = p2b + oc * 32;
        float sa = 0.f, sb = 0.f;
#pragma unroll
        for (int j = 0; j < 32; j++) {
            sa += pa[j] * a0[j];
            sb += pb[j] * a1[j];
        }
        oa[(size_t)oc * HW] = sa + sb + gs * xp[(size_t)oc * HW];
    }
}

extern "C" void kernel_launch(void* const* d_in, const int* in_sizes, int n_in,
                              void* d_out, int out_size, void* d_ws, size_t ws_size,
                              hipStream_t stream) {
    (void)in_sizes; (void)n_in; (void)out_size; (void)ws_size;
    const float* x      = (const float*)d_in[0];
    const float* shr    = (const float*)d_in[1];
    const float* femb   = (const float*)d_in[2];
    const float* noise  = (const float*)d_in[3];
    const float* gate_w = (const float*)d_in[4];
    const float* fgw    = (const float*)d_in[5];
    const float* p0     = (const float*)d_in[6];
    const float* p1     = (const float*)d_in[7];
    const float* p2     = (const float*)d_in[8];
    const float* q_w    = (const float*)d_in[9];
    const float* q_dw   = (const float*)d_in[10];
    const float* kv_w   = (const float*)d_in[11];
    const float* kv_dw  = (const float*)d_in[12];
    const float* ln_w   = (const float*)d_in[13];
    const float* ln_b   = (const float*)d_in[14];
    const float* po_w   = (const float*)d_in[15];
    const float* po_b   = (const float*)d_in[16];
    float* out = (float*)d_out;

    float* fws = (float*)d_ws;
    float* pooled = fws; fws += 1024;
    float* gsum   = fws; fws += 16;
    float* slot_g = fws; fws += 32;
    int*   slot_e = (int*)fws; fws += 32;
    float* weff   = fws; fws += 4 * 96 * 64;
    float* powf   = fws; fws += 4096;
    float* p1f    = fws; fws += 8192;
    uintptr_t a = ((uintptr_t)fws + 255) & ~(uintptr_t)255;
    unsigned short* qkvpre = (unsigned short*)a;                      // 32*96*HW bf16 = 100.7 MB
    unsigned short* qkvb   = qkvpre + (size_t)NSLOT * 96 * HW;        // 100.7 MB
    unsigned short* obuf   = qkvb + (size_t)NSLOT * 96 * HW;          // 32*32*HW bf16 = 33.6 MB
    unsigned short* attg   = qkvpre;                                  // reuse (dead after k_dw)

    k_pool<<<1024, 256, 0, stream>>>(x, pooled);
    k_gate<<<1, 64, 0, stream>>>(pooled, femb, noise, gate_w, fgw, slot_e, slot_g, gsum);
    k_weff<<<96, 256, 0, stream>>>(q_w, kv_w, p0, weff);
    k_xpose<<<32, 256, 0, stream>>>(po_w, p1, powf, p1f);
    k_qkvpre<<<NSLOT * 48, 256, 0, stream>>>(x, weff, slot_e, qkvpre);
    k_dw<<<NSLOT * 96 * 4, 256, 0, stream>>>(qkvpre, q_dw, kv_dw, slot_e, qkvb);
    k_circ<<<NSLOT * 32 * 256 / 32, 256, 0, stream>>>(qkvb, obuf);
    k_att<<<NSLOT * 64, 256, 0, stream>>>(obuf, qkvb, shr, slot_e, slot_g,
                                          powf, po_b, ln_w, ln_b, p1f, attg);
    k_comb<<<BATCH * 128, 256, 0, stream>>>(attg, x, slot_e, gsum, p2, out);
}

// Round 5
// 469.103 us; speedup vs baseline: 1.6032x; 1.0387x over previous
//
#include <hip/hip_runtime.h>
#include <hip/hip_bf16.h>

#define BATCH 16
#define DIM 64
#define RANK 32
#define H 128
#define W 128
#define HW (H*W)
#define NSLOT 32

typedef __attribute__((ext_vector_type(8))) short short8;
typedef __attribute__((ext_vector_type(4))) float f32x4;

static __device__ __forceinline__ float bu2f(unsigned short u) {
    return __uint_as_float(((unsigned)u) << 16);
}
static __device__ __forceinline__ unsigned short f2bu(float f) {
    union { __hip_bfloat16 h; unsigned short u; } cv;
    cv.h = __float2bfloat16(f);
    return cv.u;
}
static __device__ __forceinline__ float ulo(unsigned int w) { return __uint_as_float(w << 16); }
static __device__ __forceinline__ float uhi(unsigned int w) { return __uint_as_float(w & 0xffff0000u); }

// ---------------- routing ----------------
__global__ __launch_bounds__(256) void k_pool(const float* __restrict__ x,
                                              float* __restrict__ pooled) {
    int bc = blockIdx.x;  // b*64+c
    const float4* p = (const float4*)(x + (size_t)bc * HW);
    float s = 0.f;
    for (int i = threadIdx.x; i < HW / 4; i += 256) {
        float4 v = p[i];
        s += v.x + v.y + v.z + v.w;
    }
#pragma unroll
    for (int off = 32; off > 0; off >>= 1) s += __shfl_down(s, off);
    __shared__ float red[4];
    if ((threadIdx.x & 63) == 0) red[threadIdx.x >> 6] = s;
    __syncthreads();
    if (threadIdx.x == 0)
        pooled[bc] = (red[0] + red[1] + red[2] + red[3]) * (1.f / HW);
}

// writes slot table: slot s=2b+{0,1} -> (b, e, gate); plus gsum[b]
__global__ __launch_bounds__(64) void k_gate(const float* __restrict__ pooled,
                                             const float* __restrict__ freq_emb,
                                             const float* __restrict__ noise,
                                             const float* __restrict__ gate_w,
                                             const float* __restrict__ fgw,
                                             int* __restrict__ slot_e,
                                             float* __restrict__ slot_g,
                                             float* __restrict__ gsum) {
    int b = threadIdx.x;
    if (b >= BATCH) return;
    float lg[4];
    for (int e = 0; e < 4; e++) {
        float s = 0.f;
        for (int c = 0; c < 64; c++) s += pooled[b * 64 + c] * gate_w[e * 64 + c];
        for (int c = 0; c < 64; c++) s += freq_emb[b * 64 + c] * fgw[e * 64 + c];
        s += noise[b * 4 + e] * 0.25f;  // NOISE_STD = 1/E
        lg[e] = s;
    }
    float m = fmaxf(fmaxf(lg[0], lg[1]), fmaxf(lg[2], lg[3]));
    float sc[4], Z = 0.f;
    for (int e = 0; e < 4; e++) { sc[e] = expf(lg[e] - m); Z += sc[e]; }
    for (int e = 0; e < 4; e++) sc[e] /= Z;
    int i0 = 0;
    for (int e = 1; e < 4; e++) if (sc[e] > sc[i0]) i0 = e;
    int i1 = -1;
    for (int e = 0; e < 4; e++) {
        if (e == i0) continue;
        if (i1 < 0 || sc[e] > sc[i1]) i1 = e;
    }
    slot_e[2 * b] = i0;     slot_g[2 * b] = sc[i0];
    slot_e[2 * b + 1] = i1; slot_g[2 * b + 1] = sc[i1];
    gsum[b] = sc[i0] + sc[i1];
}

// ---------------- weight prep ----------------
// weff[e][j][c] = (j<32 ? q_w : kv_w)[j] . p0[:, c], emitted as bf16 hi/lo pair
// layout [e][j][c] (c contiguous) = MFMA A-operand row-major M=j, K=c
__global__ __launch_bounds__(256) void k_weff(const float* __restrict__ q_w,
                                              const float* __restrict__ kv_w,
                                              const float* __restrict__ p0,
                                              unsigned short* __restrict__ weff_h,
                                              unsigned short* __restrict__ weff_l) {
    int t = blockIdx.x * 256 + threadIdx.x;
    if (t >= 4 * 96 * 64) return;
    int c = t & 63;
    int j = (t >> 6) % 96;
    int e = t / (96 * 64);
    const float* p0p = p0 + (size_t)e * RANK * DIM;
    float s = 0.f;
    if (j < 32) {
        const float* qp = q_w + (e * 32 + j) * 32;
        for (int r = 0; r < 32; r++) s += qp[r] * p0p[r * DIM + c];
    } else {
        const float* kp = kv_w + (e * 64 + (j - 32)) * 32;
        for (int r = 0; r < 32; r++) s += kp[r] * p0p[r * DIM + c];
    }
    int idx = (e * 96 + j) * 64 + c;
    unsigned short hv = f2bu(s);
    weff_h[idx] = hv;
    weff_l[idx] = f2bu(s - bu2f(hv));
}

// transpose po_w [e][oc][c]->[e][c][oc] and p1 [e][j][c]->[e][c][j]
__global__ __launch_bounds__(256) void k_xpose(const float* __restrict__ po_w,
                                               const float* __restrict__ p1,
                                               float* __restrict__ powf,
                                               float* __restrict__ p1f) {
    int t = blockIdx.x * 256 + threadIdx.x;  // 8192
    if (t < 4096) {
        int e = t >> 10, oc = (t >> 5) & 31, c = t & 31;
        powf[(e * 32 + c) * 32 + oc] = po_w[t];
    }
    int e = t >> 11, j = (t >> 6) & 31, c = t & 63;
    p1f[(e * 64 + c) * 32 + j] = p1[t];
}

// ---------------- slot pipeline ----------------
// conv1x1 via MFMA, split-bf16 (hi/lo) for fp32-equivalent accuracy:
// C[j][p] = weff[j][c] @ x[c][p];  C ~= Ah*Bh + Ah*Bl + Al*Bh
// block = (slot, 128-px tile); LDS holds x-tile transposed [px][c] hi/lo, XOR-swizzled.
// wave w computes full M=96 over px slice [w*32, w*32+32).
__global__ __launch_bounds__(256) void k_qkvpre(const float* __restrict__ x,
                                                const unsigned short* __restrict__ weff_h,
                                                const unsigned short* __restrict__ weff_l,
                                                const int* __restrict__ slot_e,
                                                unsigned short* __restrict__ qkvpre) {
    __shared__ __align__(16) unsigned short XT[2][128 * 64];  // [hi/lo], byte = px*128 + c*2 (swz)
    int blk = blockIdx.x;
    int slot = blk >> 7;
    int p0 = (blk & 127) << 7;
    int b = slot >> 1;
    int e = slot_e[slot];

    // stage: thread t -> px = t&127, c in [ch, ch+32); transpose + hi/lo split into LDS
    {
        int t = threadIdx.x;
        int px = t & 127;
        int ch = (t >> 7) << 5;
        const float* xb = x + ((size_t)b * 64 + ch) * HW + p0 + px;
        unsigned short hv[32] __attribute__((aligned(16)));
        unsigned short lv[32] __attribute__((aligned(16)));
#pragma unroll
        for (int c = 0; c < 32; c++) {
            float v = xb[(size_t)c * HW];
            unsigned short h = f2bu(v);
            hv[c] = h;
            lv[c] = f2bu(v - bu2f(h));
        }
        int rowbyte = px * 128;
        int sw = (px & 7) << 4;
#pragma unroll
        for (int k = 0; k < 4; k++) {
            int byt = (rowbyte + (ch + k * 8) * 2) ^ sw;
            *(uint4*)((char*)XT[0] + byt) = *(const uint4*)&hv[k * 8];
            *(uint4*)((char*)XT[1] + byt) = *(const uint4*)&lv[k * 8];
        }
    }
    __syncthreads();

    int w = threadIdx.x >> 6;
    int l = threadIdx.x & 63;
    int li = l & 15, lq = l >> 4;

    // B fragments (held for whole block): B^T[px][c], lane: px = base+li, c = kt*32+lq*8
    short8 Bf[2][2][2];  // [Nt][Kt][hi/lo]
#pragma unroll
    for (int nt = 0; nt < 2; nt++) {
        int pxl = (w << 5) + (nt << 4) + li;
        int sw = (pxl & 7) << 4;
#pragma unroll
        for (int kt = 0; kt < 2; kt++) {
            int byt = (pxl * 128 + kt * 64 + lq * 16) ^ sw;
            Bf[nt][kt][0] = *(const short8*)((char*)XT[0] + byt);
            Bf[nt][kt][1] = *(const short8*)((char*)XT[1] + byt);
        }
    }

    // A fragments from global (L2-hot, 12KB/expert): A[j][c], lane: j = mt*16+li, c = kt*32+lq*8
    const unsigned short* wh = weff_h + ((size_t)e * 96 + li) * 64 + lq * 8;
    const unsigned short* wl = weff_l + ((size_t)e * 96 + li) * 64 + lq * 8;

#pragma unroll
    for (int mt = 0; mt < 6; mt++) {
        short8 Ah[2], Al[2];
#pragma unroll
        for (int kt = 0; kt < 2; kt++) {
            Ah[kt] = *(const short8*)(wh + (mt * 16) * 64 + kt * 32);
            Al[kt] = *(const short8*)(wl + (mt * 16) * 64 + kt * 32);
        }
        f32x4 acc[2] = {{0.f, 0.f, 0.f, 0.f}, {0.f, 0.f, 0.f, 0.f}};
#pragma unroll
        for (int nt = 0; nt < 2; nt++) {
#pragma unroll
            for (int kt = 0; kt < 2; kt++) {
                acc[nt] = __builtin_amdgcn_mfma_f32_16x16x32_bf16(Ah[kt], Bf[nt][kt][0], acc[nt], 0, 0, 0);
                acc[nt] = __builtin_amdgcn_mfma_f32_16x16x32_bf16(Ah[kt], Bf[nt][kt][1], acc[nt], 0, 0, 0);
                acc[nt] = __builtin_amdgcn_mfma_f32_16x16x32_bf16(Al[kt], Bf[nt][kt][0], acc[nt], 0, 0, 0);
            }
        }
        // D: row(j) = mt*16 + lq*4 + r, col(p) = p0 + w*32 + nt*16 + li
#pragma unroll
        for (int nt = 0; nt < 2; nt++) {
            int p = p0 + (w << 5) + (nt << 4) + li;
            unsigned short* op = qkvpre + ((size_t)slot * 96 + mt * 16 + lq * 4) * HW + p;
#pragma unroll
            for (int r = 0; r < 4; r++)
                op[(size_t)r * HW] = f2bu(acc[nt][r]);
        }
    }
}

// fused depthwise, LDS-tiled: ch 0..31 -> 3x3 pad1 (q_dw), ch 32..95 -> 7x7 pad3 (kv_dw)
__global__ __launch_bounds__(256) void k_dw(const unsigned short* __restrict__ qkvpre,
                                            const float* __restrict__ q_dw,
                                            const float* __restrict__ kv_dw,
                                            const int* __restrict__ slot_e,
                                            unsigned short* __restrict__ qkv) {
    __shared__ unsigned short S[38][144];   // [8 pad][128 data][8 pad], row 288B (16B-aligned)
    int t = blockIdx.x;                     // slot*(96*4) + c*4 + tile
    int tile = t & 3;
    int c = (t >> 2) % 96;
    int slot = t / (96 * 4);
    int e = slot_e[slot];
    const unsigned short* in = qkvpre + ((size_t)slot * 96 + c) * HW;
    int y0 = tile * 32 - 3;

    // hoist weights to registers (uniform broadcast loads, L1-resident)
    float wk[49];
    if (c < 32) {
        const float* wp = q_dw + (e * 32 + c) * 9;
#pragma unroll
        for (int i = 0; i < 9; i++) wk[i] = wp[i];
    } else {
        const float* wp = kv_dw + (e * 64 + (c - 32)) * 49;
#pragma unroll
        for (int i = 0; i < 49; i++) wk[i] = wp[i];
    }

    // stage 38 rows x 128 px, vectorized 8-ushort loads; zero-fill OOB rows
    for (int i = threadIdx.x; i < 38 * 16; i += 256) {
        int r = i >> 4;
        int xc = (i & 15) << 3;
        int yy = y0 + r;
        uint4 v = make_uint4(0u, 0u, 0u, 0u);
        if (yy >= 0 && yy < H) v = *(const uint4*)(in + (size_t)yy * W + xc);
        *(uint4*)&S[r][8 + xc] = v;
    }
    // zero the side pads
    for (int i = threadIdx.x; i < 38 * 2; i += 256) {
        int r = i >> 1;
        *(uint4*)&S[r][(i & 1) ? 136 : 0] = make_uint4(0u, 0u, 0u, 0u);
    }
    __syncthreads();

    int tx = (threadIdx.x & 31) * 4;        // output col base
    int ty0 = (threadIdx.x >> 5) * 4;       // output row base within tile
    float acc[4][4];
#pragma unroll
    for (int a_ = 0; a_ < 4; a_++)
#pragma unroll
        for (int b_ = 0; b_ < 4; b_++) acc[a_][b_] = 0.f;

    if (c < 32) {
#pragma unroll
        for (int rr = 0; rr < 6; rr++) {
            int srow = ty0 + 2 + rr;
            float px[12];
            uint2 w0 = *(const uint2*)&S[srow][4 + tx];
            uint2 w1 = *(const uint2*)&S[srow][8 + tx];
            uint2 w2 = *(const uint2*)&S[srow][12 + tx];
            px[0] = ulo(w0.x); px[1] = uhi(w0.x); px[2] = ulo(w0.y); px[3] = uhi(w0.y);
            px[4] = ulo(w1.x); px[5] = uhi(w1.x); px[6] = ulo(w1.y); px[7] = uhi(w1.y);
            px[8] = ulo(w2.x); px[9] = uhi(w2.x); px[10] = ulo(w2.y); px[11] = uhi(w2.y);
#pragma unroll
            for (int ly = 0; ly < 4; ly++) {
                int ky = rr - ly;
                if (ky < 0 || ky > 2) continue;
#pragma unroll
                for (int kx = 0; kx < 3; kx++) {
                    float wv = wk[ky * 3 + kx];
#pragma unroll
                    for (int j = 0; j < 4; j++) acc[ly][j] += wv * px[j + kx + 3];
                }
            }
        }
    } else {
#pragma unroll
        for (int rr = 0; rr < 10; rr++) {
            int srow = ty0 + rr;
            float px[12];
            uint2 w0 = *(const uint2*)&S[srow][4 + tx];
            uint2 w1 = *(const uint2*)&S[srow][8 + tx];
            uint2 w2 = *(const uint2*)&S[srow][12 + tx];
            px[0] = ulo(w0.x); px[1] = uhi(w0.x); px[2] = ulo(w0.y); px[3] = uhi(w0.y);
            px[4] = ulo(w1.x); px[5] = uhi(w1.x); px[6] = ulo(w1.y); px[7] = uhi(w1.y);
            px[8] = ulo(w2.x); px[9] = uhi(w2.x); px[10] = ulo(w2.y); px[11] = uhi(w2.y);
#pragma unroll
            for (int ly = 0; ly < 4; ly++) {
                int ky = rr - ly;
                if (ky < 0 || ky > 6) continue;
#pragma unroll
                for (int kx = 0; kx < 7; kx++) {
                    float wv = wk[ky * 7 + kx];
#pragma unroll
                    for (int j = 0; j < 4; j++) acc[ly][j] += wv * px[j + kx + 1];
                }
            }
        }
    }

    unsigned short* op = qkv + ((size_t)slot * 96 + c) * HW;
    int ybase = tile * 32 + ty0;
#pragma unroll
    for (int ly = 0; ly < 4; ly++) {
        ushort4 o4;
        o4.x = f2bu(acc[ly][0]); o4.y = f2bu(acc[ly][1]);
        o4.z = f2bu(acc[ly][2]); o4.w = f2bu(acc[ly][3]);
        *(ushort4*)(op + (size_t)(ybase + ly) * W + tx) = o4;
    }
}

// per-8x8-patch circular conv, FMA-bound form:
// o[i][j] = sum_mi sum_dj q[mi][(j-dj)&7] * k[(i-mi)&7][dj]
__global__ __launch_bounds__(256) void k_circ(const unsigned short* __restrict__ qkv,
                                              unsigned short* __restrict__ obuf) {
    __shared__ float Qs[32][68];
    __shared__ float Kp[32][68];
    int u = threadIdx.x >> 3;      // 0..31 block-local unit
    int i = threadIdx.x & 7;       // row
    int U = blockIdx.x * 32 + u;   // unit = (slot, c, patch)
    int patch = U & 255;
    int c = (U >> 8) & 31;
    int slot = U >> 13;
    int py = patch >> 4, px = patch & 15;
    size_t rowbase = ((size_t)slot * 96 + c) * HW + (py * 8 + i) * W + px * 8;
    uint4 qu = *(const uint4*)(qkv + rowbase);
    uint4 ku = *(const uint4*)(qkv + rowbase + (size_t)32 * HW);
    float qr[8], kr[8];
    qr[0] = ulo(qu.x); qr[1] = uhi(qu.x); qr[2] = ulo(qu.y); qr[3] = uhi(qu.y);
    qr[4] = ulo(qu.z); qr[5] = uhi(qu.z); qr[6] = ulo(qu.w); qr[7] = uhi(qu.w);
    kr[0] = ulo(ku.x); kr[1] = uhi(ku.x); kr[2] = ulo(ku.y); kr[3] = uhi(ku.y);
    kr[4] = ulo(ku.z); kr[5] = uhi(ku.z); kr[6] = ulo(ku.w); kr[7] = uhi(ku.w);
    *(float4*)&Qs[u][i * 8] = *(float4*)&qr[0];
    *(float4*)&Qs[u][i * 8 + 4] = *(float4*)&qr[4];
    *(float4*)&Kp[u][i * 8] = *(float4*)&kr[0];
    *(float4*)&Kp[u][i * 8 + 4] = *(float4*)&kr[4];
    __syncthreads();
    float acc[8];
#pragma unroll
    for (int j = 0; j < 8; j++) acc[j] = 0.f;
#pragma unroll
    for (int mi = 0; mi < 8; mi++) {
        int r = (i - mi) & 7;
        float qv[8], ka[4], kb[4];
        *(float4*)&qv[0] = *(const float4*)&Qs[u][mi * 8];
        *(float4*)&qv[4] = *(const float4*)&Qs[u][mi * 8 + 4];
        *(float4*)&ka[0] = *(const float4*)&Kp[u][r * 8];
        *(float4*)&kb[0] = *(const float4*)&Kp[u][r * 8 + 4];
#pragma unroll
        for (int j = 0; j < 8; j++) {
            float s = acc[j];
#pragma unroll
            for (int t = 0; t < 4; t++) {
                s += ka[t] * qv[(j - t) & 7];
                s += kb[t] * qv[(j - 4 - t) & 7];
            }
            acc[j] = s;
        }
    }
    size_t obase = ((size_t)slot * 32 + c) * HW + (py * 8 + i) * W + px * 8;
    uint4 ov;
    ov.x = (unsigned)f2bu(acc[0]) | ((unsigned)f2bu(acc[1]) << 16);
    ov.y = (unsigned)f2bu(acc[2]) | ((unsigned)f2bu(acc[3]) << 16);
    ov.z = (unsigned)f2bu(acc[4]) | ((unsigned)f2bu(acc[5]) << 16);
    ov.w = (unsigned)f2bu(acc[6]) | ((unsigned)f2bu(acc[7]) << 16);
    *(uint4*)(obuf + obase) = ov;
}

// per-slot attention tail: LN(obuf) -> *v -> po -> *silu(p1@shared) -> *gate
// stores attg[slot][p][32] bf16 (pixel-major: vectorized store & reload)
__global__ __launch_bounds__(256) void k_att(const unsigned short* __restrict__ obuf,
                                             const unsigned short* __restrict__ qkv,
                                             const float* __restrict__ shr,
                                             const int* __restrict__ slot_e,
                                             const float* __restrict__ slot_g,
                                             const float* __restrict__ powf,
                                             const float* __restrict__ po_b,
                                             const float* __restrict__ ln_w,
                                             const float* __restrict__ ln_b,
                                             const float* __restrict__ p1f,
                                             unsigned short* __restrict__ attg) {
    int slot = blockIdx.x >> 6;
    int p = ((blockIdx.x & 63) << 8) + threadIdx.x;
    int b = slot >> 1;
    int e = slot_e[slot];
    float g = slot_g[slot];

    // phase 1: LN(obuf)*v -> po accumulate
    const unsigned short* op = obuf + (size_t)slot * 32 * HW + p;
    float o[32];
#pragma unroll
    for (int c = 0; c < 32; c++) o[c] = bu2f(op[(size_t)c * HW]);
    float mu = 0.f;
#pragma unroll
    for (int c = 0; c < 32; c++) mu += o[c];
    mu *= (1.f / 32.f);
    float var = 0.f;
#pragma unroll
    for (int c = 0; c < 32; c++) { float d = o[c] - mu; var += d * d; }
    float rinv = rsqrtf(var * (1.f / 32.f) + 1e-5f);
    const float* powp = powf + e * 1024;
    const float* lnwp = ln_w + e * 32;
    const float* lnbp = ln_b + e * 32;
    const float* pobp = po_b + e * 32;
    const unsigned short* vp = qkv + ((size_t)slot * 96 + 64) * HW + p;
    float att[32];
#pragma unroll
    for (int j = 0; j < 32; j++) att[j] = pobp[j];
    for (int c = 0; c < 32; c++) {
        float uu = ((o[c] - mu) * rinv * lnwp[c] + lnbp[c]) * bu2f(vp[(size_t)c * HW]);
        const float* pr = powp + c * 32;
#pragma unroll
        for (int j = 0; j < 32; j++) att[j] += pr[j] * uu;
    }

    // phase 2: silu gate t = p1[e] @ shared
    float t[32];
#pragma unroll
    for (int j = 0; j < 32; j++) t[j] = 0.f;
    const float* shp = shr + (size_t)b * 64 * HW + p;
    const float* p1p = p1f + e * 2048;
    for (int c = 0; c < 64; c++) {
        float sv = shp[(size_t)c * HW];
        const float* pr = p1p + c * 32;
#pragma unroll
        for (int j = 0; j < 32; j++) t[j] += pr[j] * sv;
    }

    // gate + fold routing weight g, pack to bf16, vectorized store
    unsigned short* ap = attg + ((size_t)slot * HW + p) * 32;
    unsigned int wbuf[16];
#pragma unroll
    for (int jj = 0; jj < 16; jj++) {
        float t0 = t[2 * jj], t1 = t[2 * jj + 1];
        float a0 = g * att[2 * jj] * t0 * __builtin_amdgcn_rcpf(1.f + __expf(-t0));
        float a1 = g * att[2 * jj + 1] * t1 * __builtin_amdgcn_rcpf(1.f + __expf(-t1));
        wbuf[jj] = (unsigned)f2bu(a0) | ((unsigned)f2bu(a1) << 16);
    }
#pragma unroll
    for (int q = 0; q < 4; q++)
        *(uint4*)(ap + q * 8) = *(uint4*)&wbuf[q * 4];
}

// combine: out = p2_e0 @ attg0 + p2_e1 @ attg1 + gsum*x
// block = (b, px-tile, oc-half)
__global__ __launch_bounds__(256) void k_comb(const unsigned short* __restrict__ attg,
                                              const float* __restrict__ x,
                                              const int* __restrict__ slot_e,
                                              const float* __restrict__ gsum,
                                              const float* __restrict__ p2,
                                              float* __restrict__ out) {
    int t = blockIdx.x;
    int oh = t & 1;
    int tile = (t >> 1) & 63;
    int b = t >> 7;
    int p = (tile << 8) + threadIdx.x;

    const unsigned short* a0p = attg + ((size_t)(2 * b) * HW + p) * 32;
    const unsigned short* a1p = attg + ((size_t)(2 * b + 1) * HW + p) * 32;
    float a0[32], a1[32];
#pragma unroll
    for (int q = 0; q < 4; q++) {
        uint4 u0 = *(const uint4*)(a0p + q * 8);
        uint4 u1 = *(const uint4*)(a1p + q * 8);
        a0[q * 8 + 0] = ulo(u0.x); a0[q * 8 + 1] = uhi(u0.x);
        a0[q * 8 + 2] = ulo(u0.y); a0[q * 8 + 3] = uhi(u0.y);
        a0[q * 8 + 4] = ulo(u0.z); a0[q * 8 + 5] = uhi(u0.z);
        a0[q * 8 + 6] = ulo(u0.w); a0[q * 8 + 7] = uhi(u0.w);
        a1[q * 8 + 0] = ulo(u1.x); a1[q * 8 + 1] = uhi(u1.x);
        a1[q * 8 + 2] = ulo(u1.y); a1[q * 8 + 3] = uhi(u1.y);
        a1[q * 8 + 4] = ulo(u1.z); a1[q * 8 + 5] = uhi(u1.z);
        a1[q * 8 + 6] = ulo(u1.w); a1[q * 8 + 7] = uhi(u1.w);
    }
    int e0 = slot_e[2 * b], e1 = slot_e[2 * b + 1];
    float gs = gsum[b];
    const float* p2a = p2 + e0 * 2048 + oh * 1024;
    const float* p2b = p2 + e1 * 2048 + oh * 1024;
    const float* xp = x + ((size_t)b * 64 + oh * 32) * HW + p;
    float* oa = out + ((size_t)b * 64 + oh * 32) * HW + p;
    for (int oc = 0; oc < 32; oc++) {
        const float* pa = p2a + oc * 32;
        const float* pb = p2b + oc * 32;
        float sa = 0.f, sb = 0.f;
#pragma unroll
        for (int j = 0; j < 32; j++) {
            sa += pa[j] * a0[j];
            sb += pb[j] * a1[j];
        }
        oa[(size_t)oc * HW] = sa + sb + gs * xp[(size_t)oc * HW];
    }
}

extern "C" void kernel_launch(void* const* d_in, const int* in_sizes, int n_in,
                              void* d_out, int out_size, void* d_ws, size_t ws_size,
                              hipStream_t stream) {
    (void)in_sizes; (void)n_in; (void)out_size; (void)ws_size;
    const float* x      = (const float*)d_in[0];
    const float* shr    = (const float*)d_in[1];
    const float* femb   = (const float*)d_in[2];
    const float* noise  = (const float*)d_in[3];
    const float* gate_w = (const float*)d_in[4];
    const float* fgw    = (const float*)d_in[5];
    const float* p0     = (const float*)d_in[6];
    const float* p1     = (const float*)d_in[7];
    const float* p2     = (const float*)d_in[8];
    const float* q_w    = (const float*)d_in[9];
    const float* q_dw   = (const float*)d_in[10];
    const float* kv_w   = (const float*)d_in[11];
    const float* kv_dw  = (const float*)d_in[12];
    const float* ln_w   = (const float*)d_in[13];
    const float* ln_b   = (const float*)d_in[14];
    const float* po_w   = (const float*)d_in[15];
    const float* po_b   = (const float*)d_in[16];
    float* out = (float*)d_out;

    float* fws = (float*)d_ws;
    float* pooled = fws; fws += 1024;
    float* gsum   = fws; fws += 16;
    float* slot_g = fws; fws += 32;
    int*   slot_e = (int*)fws; fws += 32;
    unsigned short* weffh = (unsigned short*)fws; fws += 12288;  // 4*96*64 bf16 hi
    unsigned short* weffl = (unsigned short*)fws; fws += 12288;  // 4*96*64 bf16 lo
    float* powf   = fws; fws += 4096;
    float* p1f    = fws; fws += 8192;
    uintptr_t a = ((uintptr_t)fws + 255) & ~(uintptr_t)255;
    unsigned short* qkvpre = (unsigned short*)a;                      // 32*96*HW bf16 = 100.7 MB
    unsigned short* qkvb   = qkvpre + (size_t)NSLOT * 96 * HW;        // 100.7 MB
    unsigned short* obuf   = qkvb + (size_t)NSLOT * 96 * HW;          // 32*32*HW bf16 = 33.6 MB
    unsigned short* attg   = qkvpre;                                  // reuse (dead after k_dw)

    k_pool<<<1024, 256, 0, stream>>>(x, pooled);
    k_gate<<<1, 64, 0, stream>>>(pooled, femb, noise, gate_w, fgw, slot_e, slot_g, gsum);
    k_weff<<<96, 256, 0, stream>>>(q_w, kv_w, p0, weffh, weffl);
    k_xpose<<<32, 256, 0, stream>>>(po_w, p1, powf, p1f);
    k_qkvpre<<<NSLOT * 128, 256, 0, stream>>>(x, weffh, weffl, slot_e, qkvpre);
    k_dw<<<NSLOT * 96 * 4, 256, 0, stream>>>(qkvpre, q_dw, kv_dw, slot_e, qkvb);
    k_circ<<<NSLOT * 32 * 256 / 32, 256, 0, stream>>>(qkvb, obuf);
    k_att<<<NSLOT * 64, 256, 0, stream>>>(obuf, qkvb, shr, slot_e, slot_g,
                                          powf, po_b, ln_w, ln_b, p1f, attg);
    k_comb<<<BATCH * 128, 256, 0, stream>>>(attg, x, slot_e, gsum, p2, out);
}

// Round 6
// 454.206 us; speedup vs baseline: 1.6558x; 1.0328x over previous
//
#include <hip/hip_runtime.h>
#include <hip/hip_bf16.h>

#define BATCH 16
#define DIM 64
#define RANK 32
#define H 128
#define W 128
#define HW (H*W)
#define NSLOT 32

typedef __attribute__((ext_vector_type(8))) short short8;
typedef __attribute__((ext_vector_type(4))) float f32x4;

static __device__ __forceinline__ float bu2f(unsigned short u) {
    return __uint_as_float(((unsigned)u) << 16);
}
static __device__ __forceinline__ unsigned short f2bu(float f) {
    union { __hip_bfloat16 h; unsigned short u; } cv;
    cv.h = __float2bfloat16(f);
    return cv.u;
}
static __device__ __forceinline__ float ulo(unsigned int w) { return __uint_as_float(w << 16); }
static __device__ __forceinline__ float uhi(unsigned int w) { return __uint_as_float(w & 0xffff0000u); }

// ---------------- routing ----------------
__global__ __launch_bounds__(256) void k_pool(const float* __restrict__ x,
                                              float* __restrict__ pooled) {
    int bc = blockIdx.x;  // b*64+c
    const float4* p = (const float4*)(x + (size_t)bc * HW);
    float s = 0.f;
    for (int i = threadIdx.x; i < HW / 4; i += 256) {
        float4 v = p[i];
        s += v.x + v.y + v.z + v.w;
    }
#pragma unroll
    for (int off = 32; off > 0; off >>= 1) s += __shfl_down(s, off);
    __shared__ float red[4];
    if ((threadIdx.x & 63) == 0) red[threadIdx.x >> 6] = s;
    __syncthreads();
    if (threadIdx.x == 0)
        pooled[bc] = (red[0] + red[1] + red[2] + red[3]) * (1.f / HW);
}

// writes slot table: slot s=2b+{0,1} -> (b, e, gate); plus gsum[b]
__global__ __launch_bounds__(64) void k_gate(const float* __restrict__ pooled,
                                             const float* __restrict__ freq_emb,
                                             const float* __restrict__ noise,
                                             const float* __restrict__ gate_w,
                                             const float* __restrict__ fgw,
                                             int* __restrict__ slot_e,
                                             float* __restrict__ slot_g,
                                             float* __restrict__ gsum) {
    int b = threadIdx.x;
    if (b >= BATCH) return;
    float lg[4];
    for (int e = 0; e < 4; e++) {
        float s = 0.f;
        for (int c = 0; c < 64; c++) s += pooled[b * 64 + c] * gate_w[e * 64 + c];
        for (int c = 0; c < 64; c++) s += freq_emb[b * 64 + c] * fgw[e * 64 + c];
        s += noise[b * 4 + e] * 0.25f;  // NOISE_STD = 1/E
        lg[e] = s;
    }
    float m = fmaxf(fmaxf(lg[0], lg[1]), fmaxf(lg[2], lg[3]));
    float sc[4], Z = 0.f;
    for (int e = 0; e < 4; e++) { sc[e] = expf(lg[e] - m); Z += sc[e]; }
    for (int e = 0; e < 4; e++) sc[e] /= Z;
    int i0 = 0;
    for (int e = 1; e < 4; e++) if (sc[e] > sc[i0]) i0 = e;
    int i1 = -1;
    for (int e = 0; e < 4; e++) {
        if (e == i0) continue;
        if (i1 < 0 || sc[e] > sc[i1]) i1 = e;
    }
    slot_e[2 * b] = i0;     slot_g[2 * b] = sc[i0];
    slot_e[2 * b + 1] = i1; slot_g[2 * b + 1] = sc[i1];
    gsum[b] = sc[i0] + sc[i1];
}

// ---------------- weight prep ----------------
// weff[e][j][c] = (j<32 ? q_w : kv_w)[j] . p0[:, c], emitted as bf16 hi/lo pair
__global__ __launch_bounds__(256) void k_weff(const float* __restrict__ q_w,
                                              const float* __restrict__ kv_w,
                                              const float* __restrict__ p0,
                                              unsigned short* __restrict__ weff_h,
                                              unsigned short* __restrict__ weff_l) {
    int t = blockIdx.x * 256 + threadIdx.x;
    if (t >= 4 * 96 * 64) return;
    int c = t & 63;
    int j = (t >> 6) % 96;
    int e = t / (96 * 64);
    const float* p0p = p0 + (size_t)e * RANK * DIM;
    float s = 0.f;
    if (j < 32) {
        const float* qp = q_w + (e * 32 + j) * 32;
        for (int r = 0; r < 32; r++) s += qp[r] * p0p[r * DIM + c];
    } else {
        const float* kp = kv_w + (e * 64 + (j - 32)) * 32;
        for (int r = 0; r < 32; r++) s += kp[r] * p0p[r * DIM + c];
    }
    int idx = (e * 96 + j) * 64 + c;
    unsigned short hv = f2bu(s);
    weff_h[idx] = hv;
    weff_l[idx] = f2bu(s - bu2f(hv));
}

// hi/lo split po_w [e][j=32][c=32] and p1 [e][j=32][c=64] (already A-layout row-major)
__global__ __launch_bounds__(256) void k_xpose(const float* __restrict__ po_w,
                                               const float* __restrict__ p1,
                                               unsigned short* __restrict__ pow_h,
                                               unsigned short* __restrict__ pow_l,
                                               unsigned short* __restrict__ p1_h,
                                               unsigned short* __restrict__ p1_l) {
    int t = blockIdx.x * 256 + threadIdx.x;  // 8192
    if (t < 4096) {
        float v = po_w[t];
        unsigned short h = f2bu(v);
        pow_h[t] = h;
        pow_l[t] = f2bu(v - bu2f(h));
    }
    float v = p1[t];
    unsigned short h = f2bu(v);
    p1_h[t] = h;
    p1_l[t] = f2bu(v - bu2f(h));
}

// ---------------- slot pipeline ----------------
// conv1x1 via MFMA, split-bf16 (hi/lo): C ~= Ah*Bh + Ah*Bl + Al*Bh
__global__ __launch_bounds__(256) void k_qkvpre(const float* __restrict__ x,
                                                const unsigned short* __restrict__ weff_h,
                                                const unsigned short* __restrict__ weff_l,
                                                const int* __restrict__ slot_e,
                                                unsigned short* __restrict__ qkvpre) {
    __shared__ __align__(16) unsigned short XT[2][128 * 64];  // [hi/lo], byte = px*128 + c*2 (swz)
    int blk = blockIdx.x;
    int slot = blk >> 7;
    int p0 = (blk & 127) << 7;
    int b = slot >> 1;
    int e = slot_e[slot];

    {
        int t = threadIdx.x;
        int px = t & 127;
        int ch = (t >> 7) << 5;
        const float* xb = x + ((size_t)b * 64 + ch) * HW + p0 + px;
        unsigned short hv[32] __attribute__((aligned(16)));
        unsigned short lv[32] __attribute__((aligned(16)));
#pragma unroll
        for (int c = 0; c < 32; c++) {
            float v = xb[(size_t)c * HW];
            unsigned short h = f2bu(v);
            hv[c] = h;
            lv[c] = f2bu(v - bu2f(h));
        }
        int rowbyte = px * 128;
        int sw = (px & 7) << 4;
#pragma unroll
        for (int k = 0; k < 4; k++) {
            int byt = (rowbyte + (ch + k * 8) * 2) ^ sw;
            *(uint4*)((char*)XT[0] + byt) = *(const uint4*)&hv[k * 8];
            *(uint4*)((char*)XT[1] + byt) = *(const uint4*)&lv[k * 8];
        }
    }
    __syncthreads();

    int w = threadIdx.x >> 6;
    int l = threadIdx.x & 63;
    int li = l & 15, lq = l >> 4;

    short8 Bf[2][2][2];  // [Nt][Kt][hi/lo]
#pragma unroll
    for (int nt = 0; nt < 2; nt++) {
        int pxl = (w << 5) + (nt << 4) + li;
        int sw = (pxl & 7) << 4;
#pragma unroll
        for (int kt = 0; kt < 2; kt++) {
            int byt = (pxl * 128 + kt * 64 + lq * 16) ^ sw;
            Bf[nt][kt][0] = *(const short8*)((char*)XT[0] + byt);
            Bf[nt][kt][1] = *(const short8*)((char*)XT[1] + byt);
        }
    }

    const unsigned short* wh = weff_h + ((size_t)e * 96 + li) * 64 + lq * 8;
    const unsigned short* wl = weff_l + ((size_t)e * 96 + li) * 64 + lq * 8;

#pragma unroll
    for (int mt = 0; mt < 6; mt++) {
        short8 Ah[2], Al[2];
#pragma unroll
        for (int kt = 0; kt < 2; kt++) {
            Ah[kt] = *(const short8*)(wh + (mt * 16) * 64 + kt * 32);
            Al[kt] = *(const short8*)(wl + (mt * 16) * 64 + kt * 32);
        }
        f32x4 acc[2] = {{0.f, 0.f, 0.f, 0.f}, {0.f, 0.f, 0.f, 0.f}};
#pragma unroll
        for (int nt = 0; nt < 2; nt++) {
#pragma unroll
            for (int kt = 0; kt < 2; kt++) {
                acc[nt] = __builtin_amdgcn_mfma_f32_16x16x32_bf16(Ah[kt], Bf[nt][kt][0], acc[nt], 0, 0, 0);
                acc[nt] = __builtin_amdgcn_mfma_f32_16x16x32_bf16(Ah[kt], Bf[nt][kt][1], acc[nt], 0, 0, 0);
                acc[nt] = __builtin_amdgcn_mfma_f32_16x16x32_bf16(Al[kt], Bf[nt][kt][0], acc[nt], 0, 0, 0);
            }
        }
#pragma unroll
        for (int nt = 0; nt < 2; nt++) {
            int p = p0 + (w << 5) + (nt << 4) + li;
            unsigned short* op = qkvpre + ((size_t)slot * 96 + mt * 16 + lq * 4) * HW + p;
#pragma unroll
            for (int r = 0; r < 4; r++)
                op[(size_t)r * HW] = f2bu(acc[nt][r]);
        }
    }
}

// fused depthwise, LDS-tiled: ch 0..31 -> 3x3 pad1 (q_dw), ch 32..95 -> 7x7 pad3 (kv_dw)
__global__ __launch_bounds__(256) void k_dw(const unsigned short* __restrict__ qkvpre,
                                            const float* __restrict__ q_dw,
                                            const float* __restrict__ kv_dw,
                                            const int* __restrict__ slot_e,
                                            unsigned short* __restrict__ qkv) {
    __shared__ unsigned short S[38][144];   // [8 pad][128 data][8 pad], row 288B (16B-aligned)
    int t = blockIdx.x;                     // slot*(96*4) + c*4 + tile
    int tile = t & 3;
    int c = (t >> 2) % 96;
    int slot = t / (96 * 4);
    int e = slot_e[slot];
    const unsigned short* in = qkvpre + ((size_t)slot * 96 + c) * HW;
    int y0 = tile * 32 - 3;

    float wk[49];
    if (c < 32) {
        const float* wp = q_dw + (e * 32 + c) * 9;
#pragma unroll
        for (int i = 0; i < 9; i++) wk[i] = wp[i];
    } else {
        const float* wp = kv_dw + (e * 64 + (c - 32)) * 49;
#pragma unroll
        for (int i = 0; i < 49; i++) wk[i] = wp[i];
    }

    for (int i = threadIdx.x; i < 38 * 16; i += 256) {
        int r = i >> 4;
        int xc = (i & 15) << 3;
        int yy = y0 + r;
        uint4 v = make_uint4(0u, 0u, 0u, 0u);
        if (yy >= 0 && yy < H) v = *(const uint4*)(in + (size_t)yy * W + xc);
        *(uint4*)&S[r][8 + xc] = v;
    }
    for (int i = threadIdx.x; i < 38 * 2; i += 256) {
        int r = i >> 1;
        *(uint4*)&S[r][(i & 1) ? 136 : 0] = make_uint4(0u, 0u, 0u, 0u);
    }
    __syncthreads();

    int tx = (threadIdx.x & 31) * 4;
    int ty0 = (threadIdx.x >> 5) * 4;
    float acc[4][4];
#pragma unroll
    for (int a_ = 0; a_ < 4; a_++)
#pragma unroll
        for (int b_ = 0; b_ < 4; b_++) acc[a_][b_] = 0.f;

    if (c < 32) {
#pragma unroll
        for (int rr = 0; rr < 6; rr++) {
            int srow = ty0 + 2 + rr;
            float px[12];
            uint2 w0 = *(const uint2*)&S[srow][4 + tx];
            uint2 w1 = *(const uint2*)&S[srow][8 + tx];
            uint2 w2 = *(const uint2*)&S[srow][12 + tx];
            px[0] = ulo(w0.x); px[1] = uhi(w0.x); px[2] = ulo(w0.y); px[3] = uhi(w0.y);
            px[4] = ulo(w1.x); px[5] = uhi(w1.x); px[6] = ulo(w1.y); px[7] = uhi(w1.y);
            px[8] = ulo(w2.x); px[9] = uhi(w2.x); px[10] = ulo(w2.y); px[11] = uhi(w2.y);
#pragma unroll
            for (int ly = 0; ly < 4; ly++) {
                int ky = rr - ly;
                if (ky < 0 || ky > 2) continue;
#pragma unroll
                for (int kx = 0; kx < 3; kx++) {
                    float wv = wk[ky * 3 + kx];
#pragma unroll
                    for (int j = 0; j < 4; j++) acc[ly][j] += wv * px[j + kx + 3];
                }
            }
        }
    } else {
#pragma unroll
        for (int rr = 0; rr < 10; rr++) {
            int srow = ty0 + rr;
            float px[12];
            uint2 w0 = *(const uint2*)&S[srow][4 + tx];
            uint2 w1 = *(const uint2*)&S[srow][8 + tx];
            uint2 w2 = *(const uint2*)&S[srow][12 + tx];
            px[0] = ulo(w0.x); px[1] = uhi(w0.x); px[2] = ulo(w0.y); px[3] = uhi(w0.y);
            px[4] = ulo(w1.x); px[5] = uhi(w1.x); px[6] = ulo(w1.y); px[7] = uhi(w1.y);
            px[8] = ulo(w2.x); px[9] = uhi(w2.x); px[10] = ulo(w2.y); px[11] = uhi(w2.y);
#pragma unroll
            for (int ly = 0; ly < 4; ly++) {
                int ky = rr - ly;
                if (ky < 0 || ky > 6) continue;
#pragma unroll
                for (int kx = 0; kx < 7; kx++) {
                    float wv = wk[ky * 7 + kx];
#pragma unroll
                    for (int j = 0; j < 4; j++) acc[ly][j] += wv * px[j + kx + 1];
                }
            }
        }
    }

    unsigned short* op = qkv + ((size_t)slot * 96 + c) * HW;
    int ybase = tile * 32 + ty0;
#pragma unroll
    for (int ly = 0; ly < 4; ly++) {
        ushort4 o4;
        o4.x = f2bu(acc[ly][0]); o4.y = f2bu(acc[ly][1]);
        o4.z = f2bu(acc[ly][2]); o4.w = f2bu(acc[ly][3]);
        *(ushort4*)(op + (size_t)(ybase + ly) * W + tx) = o4;
    }
}

// per-8x8-patch circular conv, FMA-bound form
__global__ __launch_bounds__(256) void k_circ(const unsigned short* __restrict__ qkv,
                                              unsigned short* __restrict__ obuf) {
    __shared__ float Qs[32][68];
    __shared__ float Kp[32][68];
    int u = threadIdx.x >> 3;
    int i = threadIdx.x & 7;
    int U = blockIdx.x * 32 + u;
    int patch = U & 255;
    int c = (U >> 8) & 31;
    int slot = U >> 13;
    int py = patch >> 4, px = patch & 15;
    size_t rowbase = ((size_t)slot * 96 + c) * HW + (py * 8 + i) * W + px * 8;
    uint4 qu = *(const uint4*)(qkv + rowbase);
    uint4 ku = *(const uint4*)(qkv + rowbase + (size_t)32 * HW);
    float qr[8], kr[8];
    qr[0] = ulo(qu.x); qr[1] = uhi(qu.x); qr[2] = ulo(qu.y); qr[3] = uhi(qu.y);
    qr[4] = ulo(qu.z); qr[5] = uhi(qu.z); qr[6] = ulo(qu.w); qr[7] = uhi(qu.w);
    kr[0] = ulo(ku.x); kr[1] = uhi(ku.x); kr[2] = ulo(ku.y); kr[3] = uhi(ku.y);
    kr[4] = ulo(ku.z); kr[5] = uhi(ku.z); kr[6] = ulo(ku.w); kr[7] = uhi(ku.w);
    *(float4*)&Qs[u][i * 8] = *(float4*)&qr[0];
    *(float4*)&Qs[u][i * 8 + 4] = *(float4*)&qr[4];
    *(float4*)&Kp[u][i * 8] = *(float4*)&kr[0];
    *(float4*)&Kp[u][i * 8 + 4] = *(float4*)&kr[4];
    __syncthreads();
    float acc[8];
#pragma unroll
    for (int j = 0; j < 8; j++) acc[j] = 0.f;
#pragma unroll
    for (int mi = 0; mi < 8; mi++) {
        int r = (i - mi) & 7;
        float qv[8], ka[4], kb[4];
        *(float4*)&qv[0] = *(const float4*)&Qs[u][mi * 8];
        *(float4*)&qv[4] = *(const float4*)&Qs[u][mi * 8 + 4];
        *(float4*)&ka[0] = *(const float4*)&Kp[u][r * 8];
        *(float4*)&kb[0] = *(const float4*)&Kp[u][r * 8 + 4];
#pragma unroll
        for (int j = 0; j < 8; j++) {
            float s = acc[j];
#pragma unroll
            for (int t = 0; t < 4; t++) {
                s += ka[t] * qv[(j - t) & 7];
                s += kb[t] * qv[(j - 4 - t) & 7];
            }
            acc[j] = s;
        }
    }
    size_t obase = ((size_t)slot * 32 + c) * HW + (py * 8 + i) * W + px * 8;
    uint4 ov;
    ov.x = (unsigned)f2bu(acc[0]) | ((unsigned)f2bu(acc[1]) << 16);
    ov.y = (unsigned)f2bu(acc[2]) | ((unsigned)f2bu(acc[3]) << 16);
    ov.z = (unsigned)f2bu(acc[4]) | ((unsigned)f2bu(acc[5]) << 16);
    ov.w = (unsigned)f2bu(acc[6]) | ((unsigned)f2bu(acc[7]) << 16);
    *(uint4*)(obuf + obase) = ov;
}

// attention tail via MFMA: att = pow @ u + po_b;  t = p1 @ shared;  attg = g*att*silu(t)
// block = (slot, 128-px tile). waves 0-1 stage u=LN(obuf)*v (hi/lo); waves 2-3 stage shared.
__global__ __launch_bounds__(256) void k_att(const unsigned short* __restrict__ obuf,
                                             const unsigned short* __restrict__ qkv,
                                             const float* __restrict__ shr,
                                             const int* __restrict__ slot_e,
                                             const float* __restrict__ slot_g,
                                             const unsigned short* __restrict__ pow_h,
                                             const unsigned short* __restrict__ pow_l,
                                             const float* __restrict__ po_b,
                                             const float* __restrict__ ln_w,
                                             const float* __restrict__ ln_b,
                                             const unsigned short* __restrict__ p1_h,
                                             const unsigned short* __restrict__ p1_l,
                                             unsigned short* __restrict__ attg) {
    __shared__ __align__(16) unsigned short US[128 * 64];    // row px: 128B = [hi 32c | lo 32c], swz
    __shared__ __align__(16) unsigned short SS[128 * 128];   // row px: 256B = [hi 64c | lo 64c], swz/plane
    int blk = blockIdx.x;
    int slot = blk >> 7;
    int p0 = (blk & 127) << 7;
    int b = slot >> 1;
    int e = slot_e[slot];
    float g = slot_g[slot];

    {
        int t = threadIdx.x;
        int px = t & 127;
        int sw = (px & 7) << 4;
        if (t < 128) {
            // u = LN(obuf)*v -> bf16 hi/lo -> US (swizzled across full 128B row)
            const unsigned short* op = obuf + (size_t)slot * 32 * HW + p0 + px;
            float o[32];
#pragma unroll
            for (int c = 0; c < 32; c++) o[c] = bu2f(op[(size_t)c * HW]);
            float mu = 0.f;
#pragma unroll
            for (int c = 0; c < 32; c++) mu += o[c];
            mu *= (1.f / 32.f);
            float var = 0.f;
#pragma unroll
            for (int c = 0; c < 32; c++) { float d = o[c] - mu; var += d * d; }
            float rinv = rsqrtf(var * (1.f / 32.f) + 1e-5f);
            const float* lnwp = ln_w + e * 32;
            const float* lnbp = ln_b + e * 32;
            const unsigned short* vp = qkv + ((size_t)slot * 96 + 64) * HW + p0 + px;
            char* base = (char*)US + px * 128;
#pragma unroll
            for (int k = 0; k < 4; k++) {
                unsigned hq[4], lq_[4];
#pragma unroll
                for (int i = 0; i < 4; i++) {
                    int c0 = k * 8 + i * 2;
                    float u0 = ((o[c0] - mu) * rinv * lnwp[c0] + lnbp[c0]) * bu2f(vp[(size_t)c0 * HW]);
                    float u1 = ((o[c0 + 1] - mu) * rinv * lnwp[c0 + 1] + lnbp[c0 + 1]) * bu2f(vp[(size_t)(c0 + 1) * HW]);
                    unsigned short h0 = f2bu(u0), h1 = f2bu(u1);
                    hq[i] = (unsigned)h0 | ((unsigned)h1 << 16);
                    lq_[i] = (unsigned)f2bu(u0 - bu2f(h0)) | ((unsigned)f2bu(u1 - bu2f(h1)) << 16);
                }
                *(uint4*)(base + ((k * 16) ^ sw)) = make_uint4(hq[0], hq[1], hq[2], hq[3]);
                *(uint4*)(base + ((64 + k * 16) ^ sw)) = make_uint4(lq_[0], lq_[1], lq_[2], lq_[3]);
            }
        } else {
            // stage shared -> bf16 hi/lo -> SS (swizzled within each 128B plane)
            const float* shp = shr + (size_t)b * 64 * HW + p0 + px;
            char* base = (char*)SS + px * 256;
#pragma unroll
            for (int k = 0; k < 8; k++) {
                unsigned hq[4], lq_[4];
#pragma unroll
                for (int i = 0; i < 4; i++) {
                    int c0 = k * 8 + i * 2;
                    float v0 = shp[(size_t)c0 * HW];
                    float v1 = shp[(size_t)(c0 + 1) * HW];
                    unsigned short h0 = f2bu(v0), h1 = f2bu(v1);
                    hq[i] = (unsigned)h0 | ((unsigned)h1 << 16);
                    lq_[i] = (unsigned)f2bu(v0 - bu2f(h0)) | ((unsigned)f2bu(v1 - bu2f(h1)) << 16);
                }
                *(uint4*)(base + ((k * 16) ^ sw)) = make_uint4(hq[0], hq[1], hq[2], hq[3]);
                *(uint4*)(base + 128 + ((k * 16) ^ sw)) = make_uint4(lq_[0], lq_[1], lq_[2], lq_[3]);
            }
        }
    }
    __syncthreads();

    int w = threadIdx.x >> 6;
    int l = threadIdx.x & 63;
    int li = l & 15, lq = l >> 4;

    // B fragments
    short8 Bu[2][2];      // [nt][hi/lo]  (u, K=32)
    short8 Bs[2][2][2];   // [nt][kt][hi/lo]  (shared, K=64)
#pragma unroll
    for (int nt = 0; nt < 2; nt++) {
        int pxl = (w << 5) + (nt << 4) + li;
        int sw = (pxl & 7) << 4;
        char* ub = (char*)US + pxl * 128;
        Bu[nt][0] = *(const short8*)(ub + ((lq * 16) ^ sw));
        Bu[nt][1] = *(const short8*)(ub + ((64 + lq * 16) ^ sw));
        char* sb = (char*)SS + pxl * 256;
#pragma unroll
        for (int kt = 0; kt < 2; kt++) {
            Bs[nt][kt][0] = *(const short8*)(sb + ((kt * 64 + lq * 16) ^ sw));
            Bs[nt][kt][1] = *(const short8*)(sb + 128 + ((kt * 64 + lq * 16) ^ sw));
        }
    }

    f32x4 accA[2][2] = {{{0.f,0.f,0.f,0.f},{0.f,0.f,0.f,0.f}},{{0.f,0.f,0.f,0.f},{0.f,0.f,0.f,0.f}}};
    f32x4 accT[2][2] = {{{0.f,0.f,0.f,0.f},{0.f,0.f,0.f,0.f}},{{0.f,0.f,0.f,0.f},{0.f,0.f,0.f,0.f}}};

#pragma unroll
    for (int mt = 0; mt < 2; mt++) {
        short8 Pah = *(const short8*)(pow_h + ((size_t)e * 32 + mt * 16 + li) * 32 + lq * 8);
        short8 Pal = *(const short8*)(pow_l + ((size_t)e * 32 + mt * 16 + li) * 32 + lq * 8);
        short8 Tah[2], Tal[2];
#pragma unroll
        for (int kt = 0; kt < 2; kt++) {
            Tah[kt] = *(const short8*)(p1_h + ((size_t)e * 32 + mt * 16 + li) * 64 + kt * 32 + lq * 8);
            Tal[kt] = *(const short8*)(p1_l + ((size_t)e * 32 + mt * 16 + li) * 64 + kt * 32 + lq * 8);
        }
#pragma unroll
        for (int nt = 0; nt < 2; nt++) {
            accA[mt][nt] = __builtin_amdgcn_mfma_f32_16x16x32_bf16(Pah, Bu[nt][0], accA[mt][nt], 0, 0, 0);
            accA[mt][nt] = __builtin_amdgcn_mfma_f32_16x16x32_bf16(Pah, Bu[nt][1], accA[mt][nt], 0, 0, 0);
            accA[mt][nt] = __builtin_amdgcn_mfma_f32_16x16x32_bf16(Pal, Bu[nt][0], accA[mt][nt], 0, 0, 0);
#pragma unroll
            for (int kt = 0; kt < 2; kt++) {
                accT[mt][nt] = __builtin_amdgcn_mfma_f32_16x16x32_bf16(Tah[kt], Bs[nt][kt][0], accT[mt][nt], 0, 0, 0);
                accT[mt][nt] = __builtin_amdgcn_mfma_f32_16x16x32_bf16(Tah[kt], Bs[nt][kt][1], accT[mt][nt], 0, 0, 0);
                accT[mt][nt] = __builtin_amdgcn_mfma_f32_16x16x32_bf16(Tal[kt], Bs[nt][kt][0], accT[mt][nt], 0, 0, 0);
            }
        }
    }

    // epilogue: att += po_b; a = g*att*t*sigmoid(t); pack -> attg[slot][px][32]
    float pob[2][4];
#pragma unroll
    for (int mt = 0; mt < 2; mt++)
#pragma unroll
        for (int r = 0; r < 4; r++)
            pob[mt][r] = po_b[e * 32 + mt * 16 + lq * 4 + r];

#pragma unroll
    for (int mt = 0; mt < 2; mt++) {
#pragma unroll
        for (int nt = 0; nt < 2; nt++) {
            unsigned w2[2];
#pragma unroll
            for (int rp = 0; rp < 2; rp++) {
                float attv0 = accA[mt][nt][2 * rp] + pob[mt][2 * rp];
                float attv1 = accA[mt][nt][2 * rp + 1] + pob[mt][2 * rp + 1];
                float tv0 = accT[mt][nt][2 * rp];
                float tv1 = accT[mt][nt][2 * rp + 1];
                float a0 = g * attv0 * tv0 * __builtin_amdgcn_rcpf(1.f + __expf(-tv0));
                float a1 = g * attv1 * tv1 * __builtin_amdgcn_rcpf(1.f + __expf(-tv1));
                w2[rp] = (unsigned)f2bu(a0) | ((unsigned)f2bu(a1) << 16);
            }
            int p = p0 + (w << 5) + (nt << 4) + li;
            *(uint2*)(attg + ((size_t)slot * HW + p) * 32 + mt * 16 + lq * 4) = make_uint2(w2[0], w2[1]);
        }
    }
}

// combine: out = p2_e0 @ attg0 + p2_e1 @ attg1 + gsum*x
__global__ __launch_bounds__(256) void k_comb(const unsigned short* __restrict__ attg,
                                              const float* __restrict__ x,
                                              const int* __restrict__ slot_e,
                                              const float* __restrict__ gsum,
                                              const float* __restrict__ p2,
                                              float* __restrict__ out) {
    int t = blockIdx.x;
    int oh = t & 1;
    int tile = (t >> 1) & 63;
    int b = t >> 7;
    int p = (tile << 8) + threadIdx.x;

    const unsigned short* a0p = attg + ((size_t)(2 * b) * HW + p) * 32;
    const unsigned short* a1p = attg + ((size_t)(2 * b + 1) * HW + p) * 32;
    float a0[32], a1[32];
#pragma unroll
    for (int q = 0; q < 4; q++) {
        uint4 u0 = *(const uint4*)(a0p + q * 8);
        uint4 u1 = *(const uint4*)(a1p + q * 8);
        a0[q * 8 + 0] = ulo(u0.x); a0[q * 8 + 1] = uhi(u0.x);
        a0[q * 8 + 2] = ulo(u0.y); a0[q * 8 + 3] = uhi(u0.y);
        a0[q * 8 + 4] = ulo(u0.z); a0[q * 8 + 5] = uhi(u0.z);
        a0[q * 8 + 6] = ulo(u0.w); a0[q * 8 + 7] = uhi(u0.w);
        a1[q * 8 + 0] = ulo(u1.x); a1[q * 8 + 1] = uhi(u1.x);
        a1[q * 8 + 2] = ulo(u1.y); a1[q * 8 + 3] = uhi(u1.y);
        a1[q * 8 + 4] = ulo(u1.z); a1[q * 8 + 5] = uhi(u1.z);
        a1[q * 8 + 6] = ulo(u1.w); a1[q * 8 + 7] = uhi(u1.w);
    }
    int e0 = slot_e[2 * b], e1 = slot_e[2 * b + 1];
    float gs = gsum[b];
    const float* p2a = p2 + e0 * 2048 + oh * 1024;
    const float* p2b = p2 + e1 * 2048 + oh * 1024;
    const float* xp = x + ((size_t)b * 64 + oh * 32) * HW + p;
    float* oa = out + ((size_t)b * 64 + oh * 32) * HW + p;
    for (int oc = 0; oc < 32; oc++) {
        const float* pa = p2a + oc * 32;
        const float* pb = p2b + oc * 32;
        float sa = 0.f, sb = 0.f;
#pragma unroll
        for (int j = 0; j < 32; j++) {
            sa += pa[j] * a0[j];
            sb += pb[j] * a1[j];
        }
        oa[(size_t)oc * HW] = sa + sb + gs * xp[(size_t)oc * HW];
    }
}

extern "C" void kernel_launch(void* const* d_in, const int* in_sizes, int n_in,
                              void* d_out, int out_size, void* d_ws, size_t ws_size,
                              hipStream_t stream) {
    (void)in_sizes; (void)n_in; (void)out_size; (void)ws_size;
    const float* x      = (const float*)d_in[0];
    const float* shr    = (const float*)d_in[1];
    const float* femb   = (const float*)d_in[2];
    const float* noise  = (const float*)d_in[3];
    const float* gate_w = (const float*)d_in[4];
    const float* fgw    = (const float*)d_in[5];
    const float* p0     = (const float*)d_in[6];
    const float* p1     = (const float*)d_in[7];
    const float* p2     = (const float*)d_in[8];
    const float* q_w    = (const float*)d_in[9];
    const float* q_dw   = (const float*)d_in[10];
    const float* kv_w   = (const float*)d_in[11];
    const float* kv_dw  = (const float*)d_in[12];
    const float* ln_w   = (const float*)d_in[13];
    const float* ln_b   = (const float*)d_in[14];
    const float* po_w   = (const float*)d_in[15];
    const float* po_b   = (const float*)d_in[16];
    float* out = (float*)d_out;

    float* fws = (float*)d_ws;
    float* pooled = fws; fws += 1024;
    float* gsum   = fws; fws += 16;
    float* slot_g = fws; fws += 32;
    int*   slot_e = (int*)fws; fws += 32;
    unsigned short* weffh = (unsigned short*)fws; fws += 6144;   // 4*96*64 bf16 hi
    unsigned short* weffl = (unsigned short*)fws; fws += 6144;   // 4*96*64 bf16 lo
    unsigned short* pow_h = (unsigned short*)fws; fws += 2048;   // 4*32*32
    unsigned short* pow_l = (unsigned short*)fws; fws += 2048;
    unsigned short* p1a_h = (unsigned short*)fws; fws += 4096;   // 4*32*64
    unsigned short* p1a_l = (unsigned short*)fws; fws += 4096;
    uintptr_t a = ((uintptr_t)fws + 255) & ~(uintptr_t)255;
    unsigned short* qkvpre = (unsigned short*)a;                      // 32*96*HW bf16 = 100.7 MB
    unsigned short* qkvb   = qkvpre + (size_t)NSLOT * 96 * HW;        // 100.7 MB
    unsigned short* obuf   = qkvb + (size_t)NSLOT * 96 * HW;          // 32*32*HW bf16 = 33.6 MB
    unsigned short* attg   = qkvpre;                                  // reuse (dead after k_dw)

    k_pool<<<1024, 256, 0, stream>>>(x, pooled);
    k_gate<<<1, 64, 0, stream>>>(pooled, femb, noise, gate_w, fgw, slot_e, slot_g, gsum);
    k_weff<<<96, 256, 0, stream>>>(q_w, kv_w, p0, weffh, weffl);
    k_xpose<<<32, 256, 0, stream>>>(po_w, p1, pow_h, pow_l, p1a_h, p1a_l);
    k_qkvpre<<<NSLOT * 128, 256, 0, stream>>>(x, weffh, weffl, slot_e, qkvpre);
    k_dw<<<NSLOT * 96 * 4, 256, 0, stream>>>(qkvpre, q_dw, kv_dw, slot_e, qkvb);
    k_circ<<<NSLOT * 32 * 256 / 32, 256, 0, stream>>>(qkvb, obuf);
    k_att<<<NSLOT * 128, 256, 0, stream>>>(obuf, qkvb, shr, slot_e, slot_g,
                                           pow_h, pow_l, po_b, ln_w, ln_b,
                                           p1a_h, p1a_l, attg);
    k_comb<<<BATCH * 128, 256, 0, stream>>>(attg, x, slot_e, gsum, p2, out);
}

// Round 7
// 415.934 us; speedup vs baseline: 1.8081x; 1.0920x over previous
//
#include <hip/hip_runtime.h>
#include <hip/hip_bf16.h>

#define BATCH 16
#define DIM 64
#define RANK 32
#define H 128
#define W 128
#define HW (H*W)
#define NSLOT 32

typedef __attribute__((ext_vector_type(8))) short short8;
typedef __attribute__((ext_vector_type(4))) float f32x4;

static __device__ __forceinline__ float bu2f(unsigned short u) {
    return __uint_as_float(((unsigned)u) << 16);
}
static __device__ __forceinline__ unsigned short f2bu(float f) {
    union { __hip_bfloat16 h; unsigned short u; } cv;
    cv.h = __float2bfloat16(f);
    return cv.u;
}
static __device__ __forceinline__ float ulo(unsigned int w) { return __uint_as_float(w << 16); }
static __device__ __forceinline__ float uhi(unsigned int w) { return __uint_as_float(w & 0xffff0000u); }

// ---------------- routing ----------------
__global__ __launch_bounds__(256) void k_pool(const float* __restrict__ x,
                                              float* __restrict__ pooled) {
    int bc = blockIdx.x;  // b*64+c
    const float4* p = (const float4*)(x + (size_t)bc * HW);
    float s = 0.f;
    for (int i = threadIdx.x; i < HW / 4; i += 256) {
        float4 v = p[i];
        s += v.x + v.y + v.z + v.w;
    }
#pragma unroll
    for (int off = 32; off > 0; off >>= 1) s += __shfl_down(s, off);
    __shared__ float red[4];
    if ((threadIdx.x & 63) == 0) red[threadIdx.x >> 6] = s;
    __syncthreads();
    if (threadIdx.x == 0)
        pooled[bc] = (red[0] + red[1] + red[2] + red[3]) * (1.f / HW);
}

// writes slot table: slot s=2b+{0,1} -> (b, e, gate); plus gsum[b]
__global__ __launch_bounds__(64) void k_gate(const float* __restrict__ pooled,
                                             const float* __restrict__ freq_emb,
                                             const float* __restrict__ noise,
                                             const float* __restrict__ gate_w,
                                             const float* __restrict__ fgw,
                                             int* __restrict__ slot_e,
                                             float* __restrict__ slot_g,
                                             float* __restrict__ gsum) {
    int b = threadIdx.x;
    if (b >= BATCH) return;
    float lg[4];
    for (int e = 0; e < 4; e++) {
        float s = 0.f;
        for (int c = 0; c < 64; c++) s += pooled[b * 64 + c] * gate_w[e * 64 + c];
        for (int c = 0; c < 64; c++) s += freq_emb[b * 64 + c] * fgw[e * 64 + c];
        s += noise[b * 4 + e] * 0.25f;  // NOISE_STD = 1/E
        lg[e] = s;
    }
    float m = fmaxf(fmaxf(lg[0], lg[1]), fmaxf(lg[2], lg[3]));
    float sc[4], Z = 0.f;
    for (int e = 0; e < 4; e++) { sc[e] = expf(lg[e] - m); Z += sc[e]; }
    for (int e = 0; e < 4; e++) sc[e] /= Z;
    int i0 = 0;
    for (int e = 1; e < 4; e++) if (sc[e] > sc[i0]) i0 = e;
    int i1 = -1;
    for (int e = 0; e < 4; e++) {
        if (e == i0) continue;
        if (i1 < 0 || sc[e] > sc[i1]) i1 = e;
    }
    slot_e[2 * b] = i0;     slot_g[2 * b] = sc[i0];
    slot_e[2 * b + 1] = i1; slot_g[2 * b + 1] = sc[i1];
    gsum[b] = sc[i0] + sc[i1];
}

// ---------------- weight prep ----------------
// weff[e][j][c] = (j<32 ? q_w : kv_w)[j] . p0[:, c], emitted as bf16 hi/lo pair
__global__ __launch_bounds__(256) void k_weff(const float* __restrict__ q_w,
                                              const float* __restrict__ kv_w,
                                              const float* __restrict__ p0,
                                              unsigned short* __restrict__ weff_h,
                                              unsigned short* __restrict__ weff_l) {
    int t = blockIdx.x * 256 + threadIdx.x;
    if (t >= 4 * 96 * 64) return;
    int c = t & 63;
    int j = (t >> 6) % 96;
    int e = t / (96 * 64);
    const float* p0p = p0 + (size_t)e * RANK * DIM;
    float s = 0.f;
    if (j < 32) {
        const float* qp = q_w + (e * 32 + j) * 32;
        for (int r = 0; r < 32; r++) s += qp[r] * p0p[r * DIM + c];
    } else {
        const float* kp = kv_w + (e * 64 + (j - 32)) * 32;
        for (int r = 0; r < 32; r++) s += kp[r] * p0p[r * DIM + c];
    }
    int idx = (e * 96 + j) * 64 + c;
    unsigned short hv = f2bu(s);
    weff_h[idx] = hv;
    weff_l[idx] = f2bu(s - bu2f(hv));
}

// hi/lo split: po_w [e][32][32], p1 [e][32][64], p2 [e][64][32] (all already A-layout)
__global__ __launch_bounds__(256) void k_xpose(const float* __restrict__ po_w,
                                               const float* __restrict__ p1,
                                               const float* __restrict__ p2,
                                               unsigned short* __restrict__ pow_h,
                                               unsigned short* __restrict__ pow_l,
                                               unsigned short* __restrict__ p1_h,
                                               unsigned short* __restrict__ p1_l,
                                               unsigned short* __restrict__ p2_h,
                                               unsigned short* __restrict__ p2_l) {
    int t = blockIdx.x * 256 + threadIdx.x;  // 8192
    if (t < 4096) {
        float v = po_w[t];
        unsigned short h = f2bu(v);
        pow_h[t] = h;
        pow_l[t] = f2bu(v - bu2f(h));
    }
    {
        float v = p1[t];
        unsigned short h = f2bu(v);
        p1_h[t] = h;
        p1_l[t] = f2bu(v - bu2f(h));
    }
    {
        float v = p2[t];
        unsigned short h = f2bu(v);
        p2_h[t] = h;
        p2_l[t] = f2bu(v - bu2f(h));
    }
}

// ---------------- slot pipeline ----------------
// conv1x1 via MFMA, split-bf16 (hi/lo): C ~= Ah*Bh + Ah*Bl + Al*Bh
__global__ __launch_bounds__(256) void k_qkvpre(const float* __restrict__ x,
                                                const unsigned short* __restrict__ weff_h,
                                                const unsigned short* __restrict__ weff_l,
                                                const int* __restrict__ slot_e,
                                                unsigned short* __restrict__ qkvpre) {
    __shared__ __align__(16) unsigned short XT[2][128 * 64];  // [hi/lo], byte = px*128 + c*2 (swz)
    int blk = blockIdx.x;
    int slot = blk >> 7;
    int p0 = (blk & 127) << 7;
    int b = slot >> 1;
    int e = slot_e[slot];

    {
        int t = threadIdx.x;
        int px = t & 127;
        int ch = (t >> 7) << 5;
        const float* xb = x + ((size_t)b * 64 + ch) * HW + p0 + px;
        unsigned short hv[32] __attribute__((aligned(16)));
        unsigned short lv[32] __attribute__((aligned(16)));
#pragma unroll
        for (int c = 0; c < 32; c++) {
            float v = xb[(size_t)c * HW];
            unsigned short h = f2bu(v);
            hv[c] = h;
            lv[c] = f2bu(v - bu2f(h));
        }
        int rowbyte = px * 128;
        int sw = (px & 7) << 4;
#pragma unroll
        for (int k = 0; k < 4; k++) {
            int byt = (rowbyte + (ch + k * 8) * 2) ^ sw;
            *(uint4*)((char*)XT[0] + byt) = *(const uint4*)&hv[k * 8];
            *(uint4*)((char*)XT[1] + byt) = *(const uint4*)&lv[k * 8];
        }
    }
    __syncthreads();

    int w = threadIdx.x >> 6;
    int l = threadIdx.x & 63;
    int li = l & 15, lq = l >> 4;

    short8 Bf[2][2][2];  // [Nt][Kt][hi/lo]
#pragma unroll
    for (int nt = 0; nt < 2; nt++) {
        int pxl = (w << 5) + (nt << 4) + li;
        int sw = (pxl & 7) << 4;
#pragma unroll
        for (int kt = 0; kt < 2; kt++) {
            int byt = (pxl * 128 + kt * 64 + lq * 16) ^ sw;
            Bf[nt][kt][0] = *(const short8*)((char*)XT[0] + byt);
            Bf[nt][kt][1] = *(const short8*)((char*)XT[1] + byt);
        }
    }

    const unsigned short* wh = weff_h + ((size_t)e * 96 + li) * 64 + lq * 8;
    const unsigned short* wl = weff_l + ((size_t)e * 96 + li) * 64 + lq * 8;

#pragma unroll
    for (int mt = 0; mt < 6; mt++) {
        short8 Ah[2], Al[2];
#pragma unroll
        for (int kt = 0; kt < 2; kt++) {
            Ah[kt] = *(const short8*)(wh + (mt * 16) * 64 + kt * 32);
            Al[kt] = *(const short8*)(wl + (mt * 16) * 64 + kt * 32);
        }
        f32x4 acc[2] = {{0.f, 0.f, 0.f, 0.f}, {0.f, 0.f, 0.f, 0.f}};
#pragma unroll
        for (int nt = 0; nt < 2; nt++) {
#pragma unroll
            for (int kt = 0; kt < 2; kt++) {
                acc[nt] = __builtin_amdgcn_mfma_f32_16x16x32_bf16(Ah[kt], Bf[nt][kt][0], acc[nt], 0, 0, 0);
                acc[nt] = __builtin_amdgcn_mfma_f32_16x16x32_bf16(Ah[kt], Bf[nt][kt][1], acc[nt], 0, 0, 0);
                acc[nt] = __builtin_amdgcn_mfma_f32_16x16x32_bf16(Al[kt], Bf[nt][kt][0], acc[nt], 0, 0, 0);
            }
        }
#pragma unroll
        for (int nt = 0; nt < 2; nt++) {
            int p = p0 + (w << 5) + (nt << 4) + li;
            unsigned short* op = qkvpre + ((size_t)slot * 96 + mt * 16 + lq * 4) * HW + p;
#pragma unroll
            for (int r = 0; r < 4; r++)
                op[(size_t)r * HW] = f2bu(acc[nt][r]);
        }
    }
}

// fused depthwise, LDS-tiled: ch 0..31 -> 3x3 pad1 (q_dw), ch 32..95 -> 7x7 pad3 (kv_dw)
__global__ __launch_bounds__(256) void k_dw(const unsigned short* __restrict__ qkvpre,
                                            const float* __restrict__ q_dw,
                                            const float* __restrict__ kv_dw,
                                            const int* __restrict__ slot_e,
                                            unsigned short* __restrict__ qkv) {
    __shared__ unsigned short S[38][144];   // [8 pad][128 data][8 pad], row 288B (16B-aligned)
    int t = blockIdx.x;                     // slot*(96*4) + c*4 + tile
    int tile = t & 3;
    int c = (t >> 2) % 96;
    int slot = t / (96 * 4);
    int e = slot_e[slot];
    const unsigned short* in = qkvpre + ((size_t)slot * 96 + c) * HW;
    int y0 = tile * 32 - 3;

    float wk[49];
    if (c < 32) {
        const float* wp = q_dw + (e * 32 + c) * 9;
#pragma unroll
        for (int i = 0; i < 9; i++) wk[i] = wp[i];
    } else {
        const float* wp = kv_dw + (e * 64 + (c - 32)) * 49;
#pragma unroll
        for (int i = 0; i < 49; i++) wk[i] = wp[i];
    }

    for (int i = threadIdx.x; i < 38 * 16; i += 256) {
        int r = i >> 4;
        int xc = (i & 15) << 3;
        int yy = y0 + r;
        uint4 v = make_uint4(0u, 0u, 0u, 0u);
        if (yy >= 0 && yy < H) v = *(const uint4*)(in + (size_t)yy * W + xc);
        *(uint4*)&S[r][8 + xc] = v;
    }
    for (int i = threadIdx.x; i < 38 * 2; i += 256) {
        int r = i >> 1;
        *(uint4*)&S[r][(i & 1) ? 136 : 0] = make_uint4(0u, 0u, 0u, 0u);
    }
    __syncthreads();

    int tx = (threadIdx.x & 31) * 4;
    int ty0 = (threadIdx.x >> 5) * 4;
    float acc[4][4];
#pragma unroll
    for (int a_ = 0; a_ < 4; a_++)
#pragma unroll
        for (int b_ = 0; b_ < 4; b_++) acc[a_][b_] = 0.f;

    if (c < 32) {
#pragma unroll
        for (int rr = 0; rr < 6; rr++) {
            int srow = ty0 + 2 + rr;
            float px[12];
            uint2 w0 = *(const uint2*)&S[srow][4 + tx];
            uint2 w1 = *(const uint2*)&S[srow][8 + tx];
            uint2 w2 = *(const uint2*)&S[srow][12 + tx];
            px[0] = ulo(w0.x); px[1] = uhi(w0.x); px[2] = ulo(w0.y); px[3] = uhi(w0.y);
            px[4] = ulo(w1.x); px[5] = uhi(w1.x); px[6] = ulo(w1.y); px[7] = uhi(w1.y);
            px[8] = ulo(w2.x); px[9] = uhi(w2.x); px[10] = ulo(w2.y); px[11] = uhi(w2.y);
#pragma unroll
            for (int ly = 0; ly < 4; ly++) {
                int ky = rr - ly;
                if (ky < 0 || ky > 2) continue;
#pragma unroll
                for (int kx = 0; kx < 3; kx++) {
                    float wv = wk[ky * 3 + kx];
#pragma unroll
                    for (int j = 0; j < 4; j++) acc[ly][j] += wv * px[j + kx + 3];
                }
            }
        }
    } else {
#pragma unroll
        for (int rr = 0; rr < 10; rr++) {
            int srow = ty0 + rr;
            float px[12];
            uint2 w0 = *(const uint2*)&S[srow][4 + tx];
            uint2 w1 = *(const uint2*)&S[srow][8 + tx];
            uint2 w2 = *(const uint2*)&S[srow][12 + tx];
            px[0] = ulo(w0.x); px[1] = uhi(w0.x); px[2] = ulo(w0.y); px[3] = uhi(w0.y);
            px[4] = ulo(w1.x); px[5] = uhi(w1.x); px[6] = ulo(w1.y); px[7] = uhi(w1.y);
            px[8] = ulo(w2.x); px[9] = uhi(w2.x); px[10] = ulo(w2.y); px[11] = uhi(w2.y);
#pragma unroll
            for (int ly = 0; ly < 4; ly++) {
                int ky = rr - ly;
                if (ky < 0 || ky > 6) continue;
#pragma unroll
                for (int kx = 0; kx < 7; kx++) {
                    float wv = wk[ky * 7 + kx];
#pragma unroll
                    for (int j = 0; j < 4; j++) acc[ly][j] += wv * px[j + kx + 1];
                }
            }
        }
    }

    unsigned short* op = qkv + ((size_t)slot * 96 + c) * HW;
    int ybase = tile * 32 + ty0;
#pragma unroll
    for (int ly = 0; ly < 4; ly++) {
        ushort4 o4;
        o4.x = f2bu(acc[ly][0]); o4.y = f2bu(acc[ly][1]);
        o4.z = f2bu(acc[ly][2]); o4.w = f2bu(acc[ly][3]);
        *(ushort4*)(op + (size_t)(ybase + ly) * W + tx) = o4;
    }
}

// per-8x8-patch circular conv, FMA-bound form
__global__ __launch_bounds__(256) void k_circ(const unsigned short* __restrict__ qkv,
                                              unsigned short* __restrict__ obuf) {
    __shared__ float Qs[32][68];
    __shared__ float Kp[32][68];
    int u = threadIdx.x >> 3;
    int i = threadIdx.x & 7;
    int U = blockIdx.x * 32 + u;
    int patch = U & 255;
    int c = (U >> 8) & 31;
    int slot = U >> 13;
    int py = patch >> 4, px = patch & 15;
    size_t rowbase = ((size_t)slot * 96 + c) * HW + (py * 8 + i) * W + px * 8;
    uint4 qu = *(const uint4*)(qkv + rowbase);
    uint4 ku = *(const uint4*)(qkv + rowbase + (size_t)32 * HW);
    float qr[8], kr[8];
    qr[0] = ulo(qu.x); qr[1] = uhi(qu.x); qr[2] = ulo(qu.y); qr[3] = uhi(qu.y);
    qr[4] = ulo(qu.z); qr[5] = uhi(qu.z); qr[6] = ulo(qu.w); qr[7] = uhi(qu.w);
    kr[0] = ulo(ku.x); kr[1] = uhi(ku.x); kr[2] = ulo(ku.y); kr[3] = uhi(ku.y);
    kr[4] = ulo(ku.z); kr[5] = uhi(ku.z); kr[6] = ulo(ku.w); kr[7] = uhi(ku.w);
    *(float4*)&Qs[u][i * 8] = *(float4*)&qr[0];
    *(float4*)&Qs[u][i * 8 + 4] = *(float4*)&qr[4];
    *(float4*)&Kp[u][i * 8] = *(float4*)&kr[0];
    *(float4*)&Kp[u][i * 8 + 4] = *(float4*)&kr[4];
    __syncthreads();
    float acc[8];
#pragma unroll
    for (int j = 0; j < 8; j++) acc[j] = 0.f;
#pragma unroll
    for (int mi = 0; mi < 8; mi++) {
        int r = (i - mi) & 7;
        float qv[8], ka[4], kb[4];
        *(float4*)&qv[0] = *(const float4*)&Qs[u][mi * 8];
        *(float4*)&qv[4] = *(const float4*)&Qs[u][mi * 8 + 4];
        *(float4*)&ka[0] = *(const float4*)&Kp[u][r * 8];
        *(float4*)&kb[0] = *(const float4*)&Kp[u][r * 8 + 4];
#pragma unroll
        for (int j = 0; j < 8; j++) {
            float s = acc[j];
#pragma unroll
            for (int t = 0; t < 4; t++) {
                s += ka[t] * qv[(j - t) & 7];
                s += kb[t] * qv[(j - 4 - t) & 7];
            }
            acc[j] = s;
        }
    }
    size_t obase = ((size_t)slot * 32 + c) * HW + (py * 8 + i) * W + px * 8;
    uint4 ov;
    ov.x = (unsigned)f2bu(acc[0]) | ((unsigned)f2bu(acc[1]) << 16);
    ov.y = (unsigned)f2bu(acc[2]) | ((unsigned)f2bu(acc[3]) << 16);
    ov.z = (unsigned)f2bu(acc[4]) | ((unsigned)f2bu(acc[5]) << 16);
    ov.w = (unsigned)f2bu(acc[6]) | ((unsigned)f2bu(acc[7]) << 16);
    *(uint4*)(obuf + obase) = ov;
}

// attention tail via MFMA: att = pow @ u + po_b;  t = p1 @ shared;  attg = g*att*silu(t)
__global__ __launch_bounds__(256) void k_att(const unsigned short* __restrict__ obuf,
                                             const unsigned short* __restrict__ qkv,
                                             const float* __restrict__ shr,
                                             const int* __restrict__ slot_e,
                                             const float* __restrict__ slot_g,
                                             const unsigned short* __restrict__ pow_h,
                                             const unsigned short* __restrict__ pow_l,
                                             const float* __restrict__ po_b,
                                             const float* __restrict__ ln_w,
                                             const float* __restrict__ ln_b,
                                             const unsigned short* __restrict__ p1_h,
                                             const unsigned short* __restrict__ p1_l,
                                             unsigned short* __restrict__ attg) {
    __shared__ __align__(16) unsigned short US[128 * 64];    // row px: 128B = [hi 32c | lo 32c], swz
    __shared__ __align__(16) unsigned short SS[128 * 128];   // row px: 256B = [hi 64c | lo 64c], swz/plane
    int blk = blockIdx.x;
    int slot = blk >> 7;
    int p0 = (blk & 127) << 7;
    int b = slot >> 1;
    int e = slot_e[slot];
    float g = slot_g[slot];

    {
        int t = threadIdx.x;
        int px = t & 127;
        int sw = (px & 7) << 4;
        if (t < 128) {
            const unsigned short* op = obuf + (size_t)slot * 32 * HW + p0 + px;
            float o[32];
#pragma unroll
            for (int c = 0; c < 32; c++) o[c] = bu2f(op[(size_t)c * HW]);
            float mu = 0.f;
#pragma unroll
            for (int c = 0; c < 32; c++) mu += o[c];
            mu *= (1.f / 32.f);
            float var = 0.f;
#pragma unroll
            for (int c = 0; c < 32; c++) { float d = o[c] - mu; var += d * d; }
            float rinv = rsqrtf(var * (1.f / 32.f) + 1e-5f);
            const float* lnwp = ln_w + e * 32;
            const float* lnbp = ln_b + e * 32;
            const unsigned short* vp = qkv + ((size_t)slot * 96 + 64) * HW + p0 + px;
            char* base = (char*)US + px * 128;
#pragma unroll
            for (int k = 0; k < 4; k++) {
                unsigned hq[4], lq_[4];
#pragma unroll
                for (int i = 0; i < 4; i++) {
                    int c0 = k * 8 + i * 2;
                    float u0 = ((o[c0] - mu) * rinv * lnwp[c0] + lnbp[c0]) * bu2f(vp[(size_t)c0 * HW]);
                    float u1 = ((o[c0 + 1] - mu) * rinv * lnwp[c0 + 1] + lnbp[c0 + 1]) * bu2f(vp[(size_t)(c0 + 1) * HW]);
                    unsigned short h0 = f2bu(u0), h1 = f2bu(u1);
                    hq[i] = (unsigned)h0 | ((unsigned)h1 << 16);
                    lq_[i] = (unsigned)f2bu(u0 - bu2f(h0)) | ((unsigned)f2bu(u1 - bu2f(h1)) << 16);
                }
                *(uint4*)(base + ((k * 16) ^ sw)) = make_uint4(hq[0], hq[1], hq[2], hq[3]);
                *(uint4*)(base + ((64 + k * 16) ^ sw)) = make_uint4(lq_[0], lq_[1], lq_[2], lq_[3]);
            }
        } else {
            const float* shp = shr + (size_t)b * 64 * HW + p0 + px;
            char* base = (char*)SS + px * 256;
#pragma unroll
            for (int k = 0; k < 8; k++) {
                unsigned hq[4], lq_[4];
#pragma unroll
                for (int i = 0; i < 4; i++) {
                    int c0 = k * 8 + i * 2;
                    float v0 = shp[(size_t)c0 * HW];
                    float v1 = shp[(size_t)(c0 + 1) * HW];
                    unsigned short h0 = f2bu(v0), h1 = f2bu(v1);
                    hq[i] = (unsigned)h0 | ((unsigned)h1 << 16);
                    lq_[i] = (unsigned)f2bu(v0 - bu2f(h0)) | ((unsigned)f2bu(v1 - bu2f(h1)) << 16);
                }
                *(uint4*)(base + ((k * 16) ^ sw)) = make_uint4(hq[0], hq[1], hq[2], hq[3]);
                *(uint4*)(base + 128 + ((k * 16) ^ sw)) = make_uint4(lq_[0], lq_[1], lq_[2], lq_[3]);
            }
        }
    }
    __syncthreads();

    int w = threadIdx.x >> 6;
    int l = threadIdx.x & 63;
    int li = l & 15, lq = l >> 4;

    short8 Bu[2][2];
    short8 Bs[2][2][2];
#pragma unroll
    for (int nt = 0; nt < 2; nt++) {
        int pxl = (w << 5) + (nt << 4) + li;
        int sw = (pxl & 7) << 4;
        char* ub = (char*)US + pxl * 128;
        Bu[nt][0] = *(const short8*)(ub + ((lq * 16) ^ sw));
        Bu[nt][1] = *(const short8*)(ub + ((64 + lq * 16) ^ sw));
        char* sb = (char*)SS + pxl * 256;
#pragma unroll
        for (int kt = 0; kt < 2; kt++) {
            Bs[nt][kt][0] = *(const short8*)(sb + ((kt * 64 + lq * 16) ^ sw));
            Bs[nt][kt][1] = *(const short8*)(sb + 128 + ((kt * 64 + lq * 16) ^ sw));
        }
    }

    f32x4 accA[2][2] = {{{0.f,0.f,0.f,0.f},{0.f,0.f,0.f,0.f}},{{0.f,0.f,0.f,0.f},{0.f,0.f,0.f,0.f}}};
    f32x4 accT[2][2] = {{{0.f,0.f,0.f,0.f},{0.f,0.f,0.f,0.f}},{{0.f,0.f,0.f,0.f},{0.f,0.f,0.f,0.f}}};

#pragma unroll
    for (int mt = 0; mt < 2; mt++) {
        short8 Pah = *(const short8*)(pow_h + ((size_t)e * 32 + mt * 16 + li) * 32 + lq * 8);
        short8 Pal = *(const short8*)(pow_l + ((size_t)e * 32 + mt * 16 + li) * 32 + lq * 8);
        short8 Tah[2], Tal[2];
#pragma unroll
        for (int kt = 0; kt < 2; kt++) {
            Tah[kt] = *(const short8*)(p1_h + ((size_t)e * 32 + mt * 16 + li) * 64 + kt * 32 + lq * 8);
            Tal[kt] = *(const short8*)(p1_l + ((size_t)e * 32 + mt * 16 + li) * 64 + kt * 32 + lq * 8);
        }
#pragma unroll
        for (int nt = 0; nt < 2; nt++) {
            accA[mt][nt] = __builtin_amdgcn_mfma_f32_16x16x32_bf16(Pah, Bu[nt][0], accA[mt][nt], 0, 0, 0);
            accA[mt][nt] = __builtin_amdgcn_mfma_f32_16x16x32_bf16(Pah, Bu[nt][1], accA[mt][nt], 0, 0, 0);
            accA[mt][nt] = __builtin_amdgcn_mfma_f32_16x16x32_bf16(Pal, Bu[nt][0], accA[mt][nt], 0, 0, 0);
#pragma unroll
            for (int kt = 0; kt < 2; kt++) {
                accT[mt][nt] = __builtin_amdgcn_mfma_f32_16x16x32_bf16(Tah[kt], Bs[nt][kt][0], accT[mt][nt], 0, 0, 0);
                accT[mt][nt] = __builtin_amdgcn_mfma_f32_16x16x32_bf16(Tah[kt], Bs[nt][kt][1], accT[mt][nt], 0, 0, 0);
                accT[mt][nt] = __builtin_amdgcn_mfma_f32_16x16x32_bf16(Tal[kt], Bs[nt][kt][0], accT[mt][nt], 0, 0, 0);
            }
        }
    }

    float pob[2][4];
#pragma unroll
    for (int mt = 0; mt < 2; mt++)
#pragma unroll
        for (int r = 0; r < 4; r++)
            pob[mt][r] = po_b[e * 32 + mt * 16 + lq * 4 + r];

#pragma unroll
    for (int mt = 0; mt < 2; mt++) {
#pragma unroll
        for (int nt = 0; nt < 2; nt++) {
            unsigned w2[2];
#pragma unroll
            for (int rp = 0; rp < 2; rp++) {
                float attv0 = accA[mt][nt][2 * rp] + pob[mt][2 * rp];
                float attv1 = accA[mt][nt][2 * rp + 1] + pob[mt][2 * rp + 1];
                float tv0 = accT[mt][nt][2 * rp];
                float tv1 = accT[mt][nt][2 * rp + 1];
                float a0 = g * attv0 * tv0 * __builtin_amdgcn_rcpf(1.f + __expf(-tv0));
                float a1 = g * attv1 * tv1 * __builtin_amdgcn_rcpf(1.f + __expf(-tv1));
                w2[rp] = (unsigned)f2bu(a0) | ((unsigned)f2bu(a1) << 16);
            }
            int p = p0 + (w << 5) + (nt << 4) + li;
            *(uint2*)(attg + ((size_t)slot * HW + p) * 32 + mt * 16 + lq * 4) = make_uint2(w2[0], w2[1]);
        }
    }
}

// combine via MFMA: out[oc][p] = p2_e0[oc][:] @ attg0[p][:] + p2_e1[oc][:] @ attg1[p][:] + gs*x
// block = (b, 128-px tile); no LDS: attg is pixel-major K-contiguous (B-frag = 16B load),
// p2 hi/lo is row-major A-layout (A-frag = 16B load). B is bf16-exact -> 2 MFMAs (Ah,Al).
__global__ __launch_bounds__(256) void k_comb(const unsigned short* __restrict__ attg,
                                              const float* __restrict__ x,
                                              const int* __restrict__ slot_e,
                                              const float* __restrict__ gsum,
                                              const unsigned short* __restrict__ p2_h,
                                              const unsigned short* __restrict__ p2_l,
                                              float* __restrict__ out) {
    int blk = blockIdx.x;
    int b = blk >> 7;
    int p0 = (blk & 127) << 7;
    int e0 = slot_e[2 * b], e1 = slot_e[2 * b + 1];
    float gs = gsum[b];
    int w = threadIdx.x >> 6;
    int l = threadIdx.x & 63;
    int li = l & 15, lq = l >> 4;

    short8 B0[2], B1[2];
#pragma unroll
    for (int nt = 0; nt < 2; nt++) {
        int px = p0 + (w << 5) + (nt << 4) + li;
        B0[nt] = *(const short8*)(attg + ((size_t)(2 * b) * HW + px) * 32 + lq * 8);
        B1[nt] = *(const short8*)(attg + ((size_t)(2 * b + 1) * HW + px) * 32 + lq * 8);
    }

#pragma unroll
    for (int mt = 0; mt < 4; mt++) {
        short8 A0h = *(const short8*)(p2_h + ((size_t)e0 * 64 + mt * 16 + li) * 32 + lq * 8);
        short8 A0l = *(const short8*)(p2_l + ((size_t)e0 * 64 + mt * 16 + li) * 32 + lq * 8);
        short8 A1h = *(const short8*)(p2_h + ((size_t)e1 * 64 + mt * 16 + li) * 32 + lq * 8);
        short8 A1l = *(const short8*)(p2_l + ((size_t)e1 * 64 + mt * 16 + li) * 32 + lq * 8);
        f32x4 acc[2] = {{0.f, 0.f, 0.f, 0.f}, {0.f, 0.f, 0.f, 0.f}};
#pragma unroll
        for (int nt = 0; nt < 2; nt++) {
            acc[nt] = __builtin_amdgcn_mfma_f32_16x16x32_bf16(A0h, B0[nt], acc[nt], 0, 0, 0);
            acc[nt] = __builtin_amdgcn_mfma_f32_16x16x32_bf16(A0l, B0[nt], acc[nt], 0, 0, 0);
            acc[nt] = __builtin_amdgcn_mfma_f32_16x16x32_bf16(A1h, B1[nt], acc[nt], 0, 0, 0);
            acc[nt] = __builtin_amdgcn_mfma_f32_16x16x32_bf16(A1l, B1[nt], acc[nt], 0, 0, 0);
        }
#pragma unroll
        for (int nt = 0; nt < 2; nt++) {
            int p = p0 + (w << 5) + (nt << 4) + li;
            int ocb = mt * 16 + lq * 4;
            const float* xp = x + ((size_t)b * 64 + ocb) * HW + p;
            float* op = out + ((size_t)b * 64 + ocb) * HW + p;
#pragma unroll
            for (int r = 0; r < 4; r++)
                op[(size_t)r * HW] = acc[nt][r] + gs * xp[(size_t)r * HW];
        }
    }
}

extern "C" void kernel_launch(void* const* d_in, const int* in_sizes, int n_in,
                              void* d_out, int out_size, void* d_ws, size_t ws_size,
                              hipStream_t stream) {
    (void)in_sizes; (void)n_in; (void)out_size; (void)ws_size;
    const float* x      = (const float*)d_in[0];
    const float* shr    = (const float*)d_in[1];
    const float* femb   = (const float*)d_in[2];
    const float* noise  = (const float*)d_in[3];
    const float* gate_w = (const float*)d_in[4];
    const float* fgw    = (const float*)d_in[5];
    const float* p0     = (const float*)d_in[6];
    const float* p1     = (const float*)d_in[7];
    const float* p2     = (const float*)d_in[8];
    const float* q_w    = (const float*)d_in[9];
    const float* q_dw   = (const float*)d_in[10];
    const float* kv_w   = (const float*)d_in[11];
    const float* kv_dw  = (const float*)d_in[12];
    const float* ln_w   = (const float*)d_in[13];
    const float* ln_b   = (const float*)d_in[14];
    const float* po_w   = (const float*)d_in[15];
    const float* po_b   = (const float*)d_in[16];
    float* out = (float*)d_out;

    float* fws = (float*)d_ws;
    float* pooled = fws; fws += 1024;
    float* gsum   = fws; fws += 16;
    float* slot_g = fws; fws += 32;
    int*   slot_e = (int*)fws; fws += 32;
    unsigned short* weffh = (unsigned short*)fws; fws += 6144;   // 4*96*64 bf16 hi+pad
    unsigned short* weffl = (unsigned short*)fws; fws += 6144;
    unsigned short* pow_h = (unsigned short*)fws; fws += 2048;   // 4*32*32
    unsigned short* pow_l = (unsigned short*)fws; fws += 2048;
    unsigned short* p1a_h = (unsigned short*)fws; fws += 4096;   // 4*32*64
    unsigned short* p1a_l = (unsigned short*)fws; fws += 4096;
    unsigned short* p2a_h = (unsigned short*)fws; fws += 4096;   // 4*64*32
    unsigned short* p2a_l = (unsigned short*)fws; fws += 4096;
    uintptr_t a = ((uintptr_t)fws + 255) & ~(uintptr_t)255;
    unsigned short* qkvpre = (unsigned short*)a;                      // 32*96*HW bf16 = 100.7 MB
    unsigned short* qkvb   = qkvpre + (size_t)NSLOT * 96 * HW;        // 100.7 MB
    unsigned short* obuf   = qkvb + (size_t)NSLOT * 96 * HW;          // 32*32*HW bf16 = 33.6 MB
    unsigned short* attg   = qkvpre;                                  // reuse (dead after k_dw)

    k_pool<<<1024, 256, 0, stream>>>(x, pooled);
    k_gate<<<1, 64, 0, stream>>>(pooled, femb, noise, gate_w, fgw, slot_e, slot_g, gsum);
    k_weff<<<96, 256, 0, stream>>>(q_w, kv_w, p0, weffh, weffl);
    k_xpose<<<32, 256, 0, stream>>>(po_w, p1, p2, pow_h, pow_l, p1a_h, p1a_l, p2a_h, p2a_l);
    k_qkvpre<<<NSLOT * 128, 256, 0, stream>>>(x, weffh, weffl, slot_e, qkvpre);
    k_dw<<<NSLOT * 96 * 4, 256, 0, stream>>>(qkvpre, q_dw, kv_dw, slot_e, qkvb);
    k_circ<<<NSLOT * 32 * 256 / 32, 256, 0, stream>>>(qkvb, obuf);
    k_att<<<NSLOT * 128, 256, 0, stream>>>(obuf, qkvb, shr, slot_e, slot_g,
                                           pow_h, pow_l, po_b, ln_w, ln_b,
                                           p1a_h, p1a_l, attg);
    k_comb<<<BATCH * 128, 256, 0, stream>>>(attg, x, slot_e, gsum, p2a_h, p2a_l, out);
}